// Round 1
// baseline (279.199 us; speedup 1.0000x reference)
//
#include <hip/hip_runtime.h>
#include <cstdint>
#include <cstddef>

// ExpertMLP fused: out[e] = gelu(x[e] @ wfc[e]) @ wproj[e]
// E=32, CAP=4096, D=256, H=1024. fp32 in/out, bf16 MFMA internally.

#define NE   32
#define CAPN 4096
#define DDIM 256
#define HDIM 1024

typedef __bf16 bf16x8 __attribute__((ext_vector_type(8)));
typedef __bf16 bf16x4 __attribute__((ext_vector_type(4)));
typedef __bf16 bf16x2 __attribute__((ext_vector_type(2)));
typedef float  f32x4  __attribute__((ext_vector_type(4)));

// LDS map (dynamic, 128 KB):
//   XS : [128 m][32 slots(16B)]  row stride 512B, 64 KB, swizzled slot^=(m&7)
//   STG: weight stage, up to [256 r][8 slots] row stride 128B, 32 KB, slot^=(r&7)
//   HC : [128 m][16 slots]       row stride 256B, 32 KB, slot^=(m&7)
#define XS_OFF   0
#define STG_OFF  65536
#define HC_OFF   98304
#define LDS_BYTES 131072

#define AS1 __attribute__((address_space(1)))
#define AS3 __attribute__((address_space(3)))

__device__ __forceinline__ void gld_lds16(const void* g, void* l) {
  __builtin_amdgcn_global_load_lds((const AS1 uint32_t*)g, (AS3 uint32_t*)l, 16, 0, 0);
}

// tanh-form GELU via exp2: t = 2^(x*(c1 + c3*x^2)), gelu = x*t/(t+1) = x - x/(t+1).
// NaN-free at +/-inf; |gelu_tanh - gelu_erf| <= ~3e-3 (well under 0.101 threshold).
__device__ __forceinline__ float gelu_f(float x) {
  float x2 = x * x;
  float u  = x * __builtin_fmaf(0.1029432f, x2, 2.3022078f);
  float t  = __builtin_amdgcn_exp2f(u);
  float r  = __builtin_amdgcn_rcpf(t + 1.0f);
  return __builtin_fmaf(-x, r, x);
}

// ---------------- pre-pass: transpose + cast fp32 -> bf16 -------------------
// out[e][c][r] = (bf16) in[e][r][c]; R,C multiples of 64; grid = NE*(R/64)*(C/64)
__global__ __launch_bounds__(256) void tcast_kernel(const float* __restrict__ in,
                                                    __bf16* __restrict__ outp,
                                                    int R, int C) {
  __shared__ __bf16 tl[64][72];  // [c][r], padded
  const int cb = C >> 6;
  const int nb = (R >> 6) * cb;
  const int b  = blockIdx.x;
  const int e  = b / nb;
  const int t  = b - e * nb;
  const int br = t / cb;
  const int bc = t - br * cb;
  const float* src = in + ((size_t)e * R + (size_t)br * 64) * C + (size_t)bc * 64;
#pragma unroll
  for (int i = 0; i < 16; ++i) {
    int idx = i * 256 + threadIdx.x;
    int r = idx >> 6, c = idx & 63;
    tl[c][r] = (__bf16)src[(size_t)r * C + c];
  }
  __syncthreads();
  __bf16* dst = outp + ((size_t)e * C + (size_t)bc * 64) * R + (size_t)br * 64;
#pragma unroll
  for (int i = 0; i < 8; ++i) {
    int idx = i * 512 + threadIdx.x * 2;
    int c = idx >> 6, r = idx & 63;  // r even
    bf16x2 p;
    p[0] = tl[c][r];
    p[1] = tl[c][r + 1];
    *(bf16x2*)(dst + (size_t)c * R + r) = p;
  }
}

// ---------------- fused MLP kernel ------------------------------------------
// grid = NE * (CAPN/128) = 1024 blocks, 512 threads (8 waves), 128 KB dyn LDS.
// Swapped-operand MFMA: D = mfma(A=W^T frag, B=X^T frag) gives D[n][m]; both
// operands read as 8-consecutive-k from row-major-k LDS tiles.
__global__ __launch_bounds__(512, 2) void fused_mlp(
    const float* __restrict__ x, const __bf16* __restrict__ wfcT,
    const __bf16* __restrict__ wprojT, float* __restrict__ out) {
  extern __shared__ char smem[];
  const int tid  = threadIdx.x;
  const int lane = tid & 63;
  const int l15  = lane & 15;
  const int l4   = lane >> 4;  // 0..3
  const int w    = tid >> 6;   // wave 0..7
  const int wm   = w & 1;      // m-half (both phases)
  const int wq   = w >> 1;     // phase1: h-quad ; phase2: d-quad
  const int bid  = blockIdx.x;
  const int e    = bid >> 5;
  const int m0   = (bid & 31) << 7;

  // ---- stage X tile [128][256] fp32 -> bf16 swizzled into LDS (once) ----
  {
    const float* xb = x + ((size_t)(e * CAPN + m0)) * DDIM;
#pragma unroll
    for (int i = 0; i < 8; ++i) {
      int f2  = i * 512 + tid;  // 8-float group id, 0..4095
      int row = f2 >> 5;
      int s   = f2 & 31;
      const float4 a0 = *(const float4*)(xb + (size_t)row * DDIM + s * 8);
      const float4 a1 = *(const float4*)(xb + (size_t)row * DDIM + s * 8 + 4);
      bf16x8 v;
      v[0] = (__bf16)a0.x; v[1] = (__bf16)a0.y; v[2] = (__bf16)a0.z; v[3] = (__bf16)a0.w;
      v[4] = (__bf16)a1.x; v[5] = (__bf16)a1.y; v[6] = (__bf16)a1.z; v[7] = (__bf16)a1.w;
      int phys = (s & 24) | ((s & 7) ^ (row & 7));
      *(bf16x8*)(&smem[XS_OFF + row * 512 + phys * 16]) = v;
    }
  }

  f32x4 zero = 0.0f;
  f32x4 acc2[4][4];  // persistent: out tile [d: wq*64+fd*16][m: wm*64+fm*16]
#pragma unroll
  for (int a = 0; a < 4; ++a)
#pragma unroll
    for (int b = 0; b < 4; ++b) acc2[a][b] = zero;

  for (int c = 0; c < 8; ++c) {  // h-chunk of 128
    // ---- phase 1: D1[h 128][m 128] over K=256 (d), 4 ksteps of 64 ----
    f32x4 acc1[2][4];
#pragma unroll
    for (int a = 0; a < 2; ++a)
#pragma unroll
      for (int b = 0; b < 4; ++b) acc1[a][b] = zero;

    for (int ks = 0; ks < 4; ++ks) {
      __syncthreads();  // prior STG readers done
      // stage WfcT slab: rows h = c*128 + r (r<128), cols d = ks*64..+63 (16 KB)
      // LDS fill is linear; swizzle lives in the per-lane GLOBAL source addr.
#pragma unroll
      for (int i = 0; i < 2; ++i) {
        int o  = tid + i * 512;  // 16B-slot id
        int r  = o >> 3;
        int sl = (o & 7) ^ (r & 7);  // logical slot whose data lands here
        const __bf16* src =
            wfcT + ((size_t)(e * HDIM + c * 128 + r)) * DDIM + ks * 64 + sl * 8;
        gld_lds16(src, &smem[STG_OFF + o * 16]);
      }
      __syncthreads();  // stage visible (compiler drains vmcnt before barrier)
#pragma unroll
      for (int kk = 0; kk < 2; ++kk) {
        bf16x8 af[2], bx[4];
#pragma unroll
        for (int fh = 0; fh < 2; ++fh) {
          int r  = wq * 32 + fh * 16 + l15;
          int ph = (kk * 4 + l4) ^ (r & 7);
          af[fh] = *(const bf16x8*)(&smem[STG_OFF + r * 128 + ph * 16]);
        }
#pragma unroll
        for (int fm = 0; fm < 4; ++fm) {
          int m  = wm * 64 + fm * 16 + l15;
          int sl = ks * 8 + kk * 4 + l4;  // 0..31
          int ph = (sl & 24) | ((sl & 7) ^ (m & 7));
          bx[fm] = *(const bf16x8*)(&smem[XS_OFF + m * 512 + ph * 16]);
        }
#pragma unroll
        for (int fh = 0; fh < 2; ++fh)
#pragma unroll
          for (int fm = 0; fm < 4; ++fm)
            acc1[fh][fm] = __builtin_amdgcn_mfma_f32_16x16x32_bf16(
                af[fh], bx[fm], acc1[fh][fm], 0, 0, 0);
      }
    }

    // ---- GELU -> Hc [128 m][128 h] bf16, swizzled ----
    // D1 frag: col m = l15, rows h = wq*32+fh*16+l4*4+j (j consecutive -> b64)
#pragma unroll
    for (int fh = 0; fh < 2; ++fh) {
#pragma unroll
      for (int fm = 0; fm < 4; ++fm) {
        int m  = wm * 64 + fm * 16 + l15;
        int hl = wq * 32 + fh * 16 + l4 * 4;
        bf16x4 hv;
#pragma unroll
        for (int j = 0; j < 4; ++j) hv[j] = (__bf16)gelu_f(acc1[fh][fm][j]);
        int sl   = hl >> 3;
        int half = (hl >> 2) & 1;
        int ph   = (sl & 8) | ((sl & 7) ^ (m & 7));
        *(bf16x4*)(&smem[HC_OFF + m * 256 + ph * 16 + half * 8]) = hv;
      }
    }
    __syncthreads();  // Hc visible to all; phase-1 STG reads done

    // ---- phase 2: acc2 += WprojT-frag @ Hc-frag, K = 128 (2 ksteps of 64) ----
    for (int ks2 = 0; ks2 < 2; ++ks2) {
      if (ks2) __syncthreads();
      // stage WprojT slab: rows d = r (r<256), cols h = c*128 + ks2*64..+63 (32 KB)
#pragma unroll
      for (int i = 0; i < 4; ++i) {
        int o  = tid + i * 512;
        int r  = o >> 3;  // 0..255
        int sl = (o & 7) ^ (r & 7);
        const __bf16* src =
            wprojT + ((size_t)(e * DDIM + r)) * HDIM + c * 128 + ks2 * 64 + sl * 8;
        gld_lds16(src, &smem[STG_OFF + o * 16]);
      }
      __syncthreads();
#pragma unroll
      for (int kk = 0; kk < 2; ++kk) {
        bf16x8 af[4], bx[4];
#pragma unroll
        for (int fd = 0; fd < 4; ++fd) {
          int r  = wq * 64 + fd * 16 + l15;
          int ph = (kk * 4 + l4) ^ (r & 7);
          af[fd] = *(const bf16x8*)(&smem[STG_OFF + r * 128 + ph * 16]);
        }
#pragma unroll
        for (int fm = 0; fm < 4; ++fm) {
          int m  = wm * 64 + fm * 16 + l15;
          int sl = ks2 * 8 + kk * 4 + l4;  // 0..15
          int ph = (sl & 8) | ((sl & 7) ^ (m & 7));
          bx[fm] = *(const bf16x8*)(&smem[HC_OFF + m * 256 + ph * 16]);
        }
#pragma unroll
        for (int fd = 0; fd < 4; ++fd)
#pragma unroll
          for (int fm = 0; fm < 4; ++fm)
            acc2[fd][fm] = __builtin_amdgcn_mfma_f32_16x16x32_bf16(
                af[fd], bx[fm], acc2[fd][fm], 0, 0, 0);
      }
    }
    // next chunk's phase-1 leading barrier protects STG and Hc reuse
  }

  // ---- epilogue: fp32 out. D2 frag: col m = l15, rows d = l4*4+j (float4) ----
#pragma unroll
  for (int fd = 0; fd < 4; ++fd) {
#pragma unroll
    for (int fm = 0; fm < 4; ++fm) {
      int m = m0 + wm * 64 + fm * 16 + l15;
      int d = wq * 64 + fd * 16 + l4 * 4;
      *(f32x4*)(out + ((size_t)(e * CAPN + m)) * DDIM + d) = acc2[fd][fm];
    }
  }
}

extern "C" void kernel_launch(void* const* d_in, const int* in_sizes, int n_in,
                              void* d_out, int out_size, void* d_ws, size_t ws_size,
                              hipStream_t stream) {
  (void)in_sizes; (void)n_in; (void)out_size; (void)ws_size;
  const float* x     = (const float*)d_in[0];
  const float* wfc   = (const float*)d_in[1];   // [E][D][H]
  const float* wproj = (const float*)d_in[2];   // [E][H][D]
  float* out = (float*)d_out;

  // ws: WfcT bf16 [E][H][D] (16.78 MB) | WprojT bf16 [E][D][H] (16.78 MB)
  __bf16* wfcT   = (__bf16*)d_ws;
  __bf16* wprojT = (__bf16*)((char*)d_ws + (size_t)NE * DDIM * HDIM * sizeof(__bf16));

  hipFuncSetAttribute((const void*)fused_mlp,
                      hipFuncAttributeMaxDynamicSharedMemorySize, LDS_BYTES);

  tcast_kernel<<<dim3(NE * 64), dim3(256), 0, stream>>>(wfc, wfcT, DDIM, HDIM);
  tcast_kernel<<<dim3(NE * 64), dim3(256), 0, stream>>>(wproj, wprojT, HDIM, DDIM);
  fused_mlp<<<dim3(NE * 32), dim3(512), LDS_BYTES, stream>>>(x, wfcT, wprojT, out);
}

// Round 2
// 243.884 us; speedup vs baseline: 1.1448x; 1.1448x over previous
//
#include <hip/hip_runtime.h>
#include <cstdint>
#include <cstddef>

// ExpertMLP fused: out[e] = gelu(x[e] @ wfc[e]) @ wproj[e]
// E=32, CAP=4096, D=256, H=1024. fp32 in/out, bf16 MFMA internally.
// Round 2: uniform 16KB slab stream, counted vmcnt(2) pipeline (T3+T4),
// raw s_barrier, setprio around MFMA clusters (T5).

#define NE   32
#define CAPN 4096
#define DDIM 256
#define HDIM 1024

typedef __bf16 bf16x8 __attribute__((ext_vector_type(8)));
typedef __bf16 bf16x4 __attribute__((ext_vector_type(4)));
typedef __bf16 bf16x2 __attribute__((ext_vector_type(2)));
typedef float  f32x4  __attribute__((ext_vector_type(4)));

// LDS map (dynamic, 128 KB):
//   XS : [128 m][32 slots(16B)] stride 512B, 64 KB, slot low3 ^= (m&7)
//   STG: 2 x 16KB slabs, each [128 r][8 slots] stride 128B, slot ^= (r&7)
//   HC : [128 m][16 slots]      stride 256B, 32 KB, slot low3 ^= (m&7)
#define XS_OFF   0
#define STG_OFF  65536
#define STG_SZ   16384
#define HC_OFF   98304
#define LDS_BYTES 131072

#define AS1 __attribute__((address_space(1)))
#define AS3 __attribute__((address_space(3)))

__device__ __forceinline__ void gld_lds16(const void* g, void* l) {
  __builtin_amdgcn_global_load_lds((const AS1 uint32_t*)g, (AS3 uint32_t*)l, 16, 0, 0);
}

// tanh-form GELU via exp2; |err vs erf-GELU| <~3e-3, NaN-free.
__device__ __forceinline__ float gelu_f(float x) {
  float x2 = x * x;
  float u  = x * __builtin_fmaf(0.1029432f, x2, 2.3022078f);
  float t  = __builtin_amdgcn_exp2f(u);
  float r  = __builtin_amdgcn_rcpf(t + 1.0f);
  return __builtin_fmaf(-x, r, x);
}

// ---------------- pre-pass: transpose + cast fp32 -> bf16 -------------------
__global__ __launch_bounds__(256) void tcast_kernel(const float* __restrict__ in,
                                                    __bf16* __restrict__ outp,
                                                    int R, int C) {
  __shared__ __bf16 tl[64][72];
  const int cb = C >> 6;
  const int nb = (R >> 6) * cb;
  const int b  = blockIdx.x;
  const int e  = b / nb;
  const int t  = b - e * nb;
  const int br = t / cb;
  const int bc = t - br * cb;
  const float* src = in + ((size_t)e * R + (size_t)br * 64) * C + (size_t)bc * 64;
#pragma unroll
  for (int i = 0; i < 16; ++i) {
    int idx = i * 256 + threadIdx.x;
    int r = idx >> 6, c = idx & 63;
    tl[c][r] = (__bf16)src[(size_t)r * C + c];
  }
  __syncthreads();
  __bf16* dst = outp + ((size_t)e * C + (size_t)bc * 64) * R + (size_t)br * 64;
#pragma unroll
  for (int i = 0; i < 8; ++i) {
    int idx = i * 512 + threadIdx.x * 2;
    int c = idx >> 6, r = idx & 63;
    bf16x2 p;
    p[0] = tl[c][r];
    p[1] = tl[c][r + 1];
    *(bf16x2*)(dst + (size_t)c * R + r) = p;
  }
}

// ---------------- fused MLP kernel ------------------------------------------
// grid = NE * (CAPN/128) = 1024 blocks, 512 threads (8 waves), 128 KB dyn LDS.
// Slab stream per block: 64 slabs of 16KB, [128 r][64 k] bf16.
//   slab s: c = s>>3, t = s&7.
//   t<4  (P1): Wfc^T rows h = c*128+r, cols d = t*64..+63
//   t>=4 (P2): j=t-4, hd=j&1, hh=j>>1: Wproj^T rows d = hd*128+r,
//              cols h = c*128 + hh*64 ..+63
__global__ __launch_bounds__(512, 2) void fused_mlp(
    const float* __restrict__ x, const __bf16* __restrict__ wfcT,
    const __bf16* __restrict__ wprojT, float* __restrict__ out) {
  extern __shared__ char smem[];
  const int tid  = threadIdx.x;
  const int lane = tid & 63;
  const int l15  = lane & 15;
  const int l4   = lane >> 4;   // 0..3
  const int w    = tid >> 6;    // wave 0..7
  const int wm   = w & 1;       // m-half
  const int q    = w >> 1;      // 0..3: P1 h-quad; P2 d-sub-quad
  const int bid  = blockIdx.x;
  const int e    = bid >> 5;
  const int m0   = (bid & 31) << 7;

  // slab stage: LDS fill linear in lane (gld_lds requirement); swizzle lives
  // in the per-lane GLOBAL source address.
  auto stage_slab = [&](int s) {
    const int buf = s & 1;
    const int c   = s >> 3;
    const int t   = s & 7;
    const __bf16* base;
    size_t rs;
    if (t < 4) {
      base = wfcT + (size_t)(e * HDIM + c * 128) * DDIM + t * 64;
      rs   = DDIM;
    } else {
      const int j = t - 4;
      base = wprojT + (size_t)(e * DDIM + (j & 1) * 128) * HDIM + c * 128 + (j >> 1) * 64;
      rs   = HDIM;
    }
#pragma unroll
    for (int i = 0; i < 2; ++i) {
      int o  = tid + i * 512;
      int r  = o >> 3;
      int sl = (o & 7) ^ (r & 7);
      gld_lds16(base + (size_t)r * rs + sl * 8, &smem[STG_OFF + buf * STG_SZ + o * 16]);
    }
  };

  // ---- stage X tile [128][256] fp32 -> bf16 swizzled into LDS (once) ----
  {
    const float* xb = x + ((size_t)(e * CAPN + m0)) * DDIM;
#pragma unroll
    for (int i = 0; i < 8; ++i) {
      int f2  = i * 512 + tid;
      int row = f2 >> 5;
      int s   = f2 & 31;
      const float4 a0 = *(const float4*)(xb + (size_t)row * DDIM + s * 8);
      const float4 a1 = *(const float4*)(xb + (size_t)row * DDIM + s * 8 + 4);
      bf16x8 v;
      v[0] = (__bf16)a0.x; v[1] = (__bf16)a0.y; v[2] = (__bf16)a0.z; v[3] = (__bf16)a0.w;
      v[4] = (__bf16)a1.x; v[5] = (__bf16)a1.y; v[6] = (__bf16)a1.z; v[7] = (__bf16)a1.w;
      int phys = (s & 24) | ((s & 7) ^ (row & 7));
      *(bf16x8*)(&smem[XS_OFF + row * 512 + phys * 16]) = v;
    }
  }

  // prologue: two slabs in flight
  stage_slab(0);
  stage_slab(1);

  f32x4 zero = 0.0f;
  f32x4 acc2[4][4];  // [a][fm]: d = (a>>1)*128 + q*32 + (a&1)*16 ; m = wm*64+fm*16
#pragma unroll
  for (int a = 0; a < 4; ++a)
#pragma unroll
    for (int b = 0; b < 4; ++b) acc2[a][b] = zero;

#define SLAB_PRE(lastp)                                                        \
  do {                                                                         \
    if (lastp) asm volatile("s_waitcnt vmcnt(0) lgkmcnt(0)" ::: "memory");     \
    else       asm volatile("s_waitcnt vmcnt(2) lgkmcnt(0)" ::: "memory");     \
    __builtin_amdgcn_s_barrier();                                              \
    __builtin_amdgcn_sched_barrier(0);                                         \
  } while (0)

#define SLAB_POST(sidx)                                                        \
  do {                                                                         \
    __builtin_amdgcn_sched_barrier(0);                                         \
    __builtin_amdgcn_s_barrier();                                              \
    if ((sidx) + 2 < 64) stage_slab((sidx) + 2);                               \
  } while (0)

  for (int c = 0; c < 8; ++c) {
    // ---- phase 1: acc1[h 128][m 128] over K=256, 4 slabs of K=64 ----
    f32x4 acc1[2][4];
#pragma unroll
    for (int a = 0; a < 2; ++a)
#pragma unroll
      for (int b = 0; b < 4; ++b) acc1[a][b] = zero;

#pragma unroll
    for (int ks = 0; ks < 4; ++ks) {
      const int sidx = c * 8 + ks;
      const int buf  = sidx & 1;
      SLAB_PRE(false);
      bf16x8 a0[2], a1[2], b0[4], b1[4];
#pragma unroll
      for (int fh = 0; fh < 2; ++fh) {
        int r = q * 32 + fh * 16 + l15;
        a0[fh] = *(const bf16x8*)(&smem[STG_OFF + buf * STG_SZ + r * 128 + ((0 * 4 + l4) ^ (r & 7)) * 16]);
        a1[fh] = *(const bf16x8*)(&smem[STG_OFF + buf * STG_SZ + r * 128 + ((1 * 4 + l4) ^ (r & 7)) * 16]);
      }
#pragma unroll
      for (int fm = 0; fm < 4; ++fm) {
        int m   = wm * 64 + fm * 16 + l15;
        int sl0 = ks * 8 + 0 * 4 + l4;
        int sl1 = ks * 8 + 1 * 4 + l4;
        int p0  = (sl0 & 24) | ((sl0 & 7) ^ (m & 7));
        int p1  = (sl1 & 24) | ((sl1 & 7) ^ (m & 7));
        b0[fm] = *(const bf16x8*)(&smem[XS_OFF + m * 512 + p0 * 16]);
        b1[fm] = *(const bf16x8*)(&smem[XS_OFF + m * 512 + p1 * 16]);
      }
      __builtin_amdgcn_s_setprio(1);
#pragma unroll
      for (int fh = 0; fh < 2; ++fh)
#pragma unroll
        for (int fm = 0; fm < 4; ++fm)
          acc1[fh][fm] = __builtin_amdgcn_mfma_f32_16x16x32_bf16(a0[fh], b0[fm], acc1[fh][fm], 0, 0, 0);
#pragma unroll
      for (int fh = 0; fh < 2; ++fh)
#pragma unroll
        for (int fm = 0; fm < 4; ++fm)
          acc1[fh][fm] = __builtin_amdgcn_mfma_f32_16x16x32_bf16(a1[fh], b1[fm], acc1[fh][fm], 0, 0, 0);
      __builtin_amdgcn_s_setprio(0);
      SLAB_POST(sidx);
    }

    // ---- GELU -> HC [128 m][128 h] bf16 (visibility via next SLAB_PRE) ----
#pragma unroll
    for (int fh = 0; fh < 2; ++fh) {
#pragma unroll
      for (int fm = 0; fm < 4; ++fm) {
        int m  = wm * 64 + fm * 16 + l15;
        int hl = q * 32 + fh * 16 + l4 * 4;
        bf16x4 hv;
#pragma unroll
        for (int j = 0; j < 4; ++j) hv[j] = (__bf16)gelu_f(acc1[fh][fm][j]);
        int sl   = hl >> 3;
        int half = (hl >> 2) & 1;
        int ph   = (sl & 8) | ((sl & 7) ^ (m & 7));
        *(bf16x4*)(&smem[HC_OFF + m * 256 + ph * 16 + half * 8]) = hv;
      }
    }

    // ---- phase 2: acc2 += Wproj^T-frag @ HC-frag, 4 slabs of K=64 ----
#pragma unroll
    for (int j = 0; j < 4; ++j) {
      const int sidx = c * 8 + 4 + j;
      const int buf  = sidx & 1;
      const int hd   = j & 1;
      const int hh   = j >> 1;
      const bool last = (c == 7) && (j == 3);
      SLAB_PRE(last);
      bf16x8 a0[2], a1[2], b0[4], b1[4];
#pragma unroll
      for (int fd = 0; fd < 2; ++fd) {
        int r = q * 32 + fd * 16 + l15;
        a0[fd] = *(const bf16x8*)(&smem[STG_OFF + buf * STG_SZ + r * 128 + ((0 * 4 + l4) ^ (r & 7)) * 16]);
        a1[fd] = *(const bf16x8*)(&smem[STG_OFF + buf * STG_SZ + r * 128 + ((1 * 4 + l4) ^ (r & 7)) * 16]);
      }
#pragma unroll
      for (int fm = 0; fm < 4; ++fm) {
        int m   = wm * 64 + fm * 16 + l15;
        int sl0 = hh * 8 + 0 * 4 + l4;
        int sl1 = hh * 8 + 1 * 4 + l4;
        int p0  = (sl0 & 8) | ((sl0 & 7) ^ (m & 7));
        int p1  = (sl1 & 8) | ((sl1 & 7) ^ (m & 7));
        b0[fm] = *(const bf16x8*)(&smem[HC_OFF + m * 256 + p0 * 16]);
        b1[fm] = *(const bf16x8*)(&smem[HC_OFF + m * 256 + p1 * 16]);
      }
      __builtin_amdgcn_s_setprio(1);
#pragma unroll
      for (int fd = 0; fd < 2; ++fd)
#pragma unroll
        for (int fm = 0; fm < 4; ++fm)
          acc2[hd * 2 + fd][fm] = __builtin_amdgcn_mfma_f32_16x16x32_bf16(a0[fd], b0[fm], acc2[hd * 2 + fd][fm], 0, 0, 0);
#pragma unroll
      for (int fd = 0; fd < 2; ++fd)
#pragma unroll
        for (int fm = 0; fm < 4; ++fm)
          acc2[hd * 2 + fd][fm] = __builtin_amdgcn_mfma_f32_16x16x32_bf16(a1[fd], b1[fm], acc2[hd * 2 + fd][fm], 0, 0, 0);
      __builtin_amdgcn_s_setprio(0);
      SLAB_POST(sidx);
    }
  }

  // ---- epilogue: D2 frag col m = l15, rows d = l4*4+j (float4 stores) ----
#pragma unroll
  for (int a = 0; a < 4; ++a) {
#pragma unroll
    for (int fm = 0; fm < 4; ++fm) {
      int m = m0 + wm * 64 + fm * 16 + l15;
      int d = (a >> 1) * 128 + q * 32 + (a & 1) * 16 + l4 * 4;
      *(f32x4*)(out + ((size_t)(e * CAPN + m)) * DDIM + d) = acc2[a][fm];
    }
  }
}

extern "C" void kernel_launch(void* const* d_in, const int* in_sizes, int n_in,
                              void* d_out, int out_size, void* d_ws, size_t ws_size,
                              hipStream_t stream) {
  (void)in_sizes; (void)n_in; (void)out_size; (void)ws_size;
  const float* x     = (const float*)d_in[0];
  const float* wfc   = (const float*)d_in[1];   // [E][D][H]
  const float* wproj = (const float*)d_in[2];   // [E][H][D]
  float* out = (float*)d_out;

  __bf16* wfcT   = (__bf16*)d_ws;
  __bf16* wprojT = (__bf16*)((char*)d_ws + (size_t)NE * DDIM * HDIM * sizeof(__bf16));

  hipFuncSetAttribute((const void*)fused_mlp,
                      hipFuncAttributeMaxDynamicSharedMemorySize, LDS_BYTES);

  tcast_kernel<<<dim3(NE * 64), dim3(256), 0, stream>>>(wfc, wfcT, DDIM, HDIM);
  tcast_kernel<<<dim3(NE * 64), dim3(256), 0, stream>>>(wproj, wprojT, HDIM, DDIM);
  fused_mlp<<<dim3(NE * 32), dim3(512), LDS_BYTES, stream>>>(x, wfcT, wprojT, out);
}

// Round 3
// 228.060 us; speedup vs baseline: 1.2242x; 1.0694x over previous
//
#include <hip/hip_runtime.h>
#include <cstdint>
#include <cstddef>

// ExpertMLP fused: out[e] = gelu(x[e] @ wfc[e]) @ wproj[e]
// E=32, CAP=4096, D=256, H=1024. fp32 in/out, bf16 MFMA internally.
// Round 3: 64x64 wave tiles (0.5KB LDS-read per 16384 FLOP), chunk=256h,
// 160KB LDS (XS 64K + HC 64K + 2x16K slab stage), counted vmcnt(2) pipeline.
// Fallback to round-2 128KB kernel if 160KB dynamic LDS is rejected.

#define NE   32
#define CAPN 4096
#define DDIM 256
#define HDIM 1024

typedef __bf16 bf16x8 __attribute__((ext_vector_type(8)));
typedef __bf16 bf16x4 __attribute__((ext_vector_type(4)));
typedef __bf16 bf16x2 __attribute__((ext_vector_type(2)));
typedef float  f32x4  __attribute__((ext_vector_type(4)));

#define AS1 __attribute__((address_space(1)))
#define AS3 __attribute__((address_space(3)))

__device__ __forceinline__ void gld_lds16(const void* g, void* l) {
  __builtin_amdgcn_global_load_lds((const AS1 uint32_t*)g, (AS3 uint32_t*)l, 16, 0, 0);
}

// tanh-form GELU via exp2; |err vs erf-GELU| <~3e-3, NaN-free.
__device__ __forceinline__ float gelu_f(float x) {
  float x2 = x * x;
  float u  = x * __builtin_fmaf(0.1029432f, x2, 2.3022078f);
  float t  = __builtin_amdgcn_exp2f(u);
  float r  = __builtin_amdgcn_rcpf(t + 1.0f);
  return __builtin_fmaf(-x, r, x);
}

#define SLAB_PRE(lastp)                                                        \
  do {                                                                         \
    if (lastp) asm volatile("s_waitcnt vmcnt(0) lgkmcnt(0)" ::: "memory");     \
    else       asm volatile("s_waitcnt vmcnt(2) lgkmcnt(0)" ::: "memory");     \
    __builtin_amdgcn_s_barrier();                                              \
    __builtin_amdgcn_sched_barrier(0);                                         \
  } while (0)

#define SLAB_POST_160(sidx)                                                    \
  do {                                                                         \
    __builtin_amdgcn_sched_barrier(0);                                         \
    __builtin_amdgcn_s_barrier();                                              \
    if ((sidx) + 2 < 64) stage_slab((sidx) + 2);                               \
  } while (0)

#define SLAB_POST_128(sidx)                                                    \
  do {                                                                         \
    __builtin_amdgcn_sched_barrier(0);                                         \
    __builtin_amdgcn_s_barrier();                                              \
    if ((sidx) + 2 < 64) stage_slab((sidx) + 2);                               \
  } while (0)

// ---------------- pre-pass: transpose + cast fp32 -> bf16 -------------------
__global__ __launch_bounds__(256) void tcast_kernel(const float* __restrict__ in,
                                                    __bf16* __restrict__ outp,
                                                    int R, int C) {
  __shared__ __bf16 tl[64][72];
  const int cb = C >> 6;
  const int nb = (R >> 6) * cb;
  const int b  = blockIdx.x;
  const int e  = b / nb;
  const int t  = b - e * nb;
  const int br = t / cb;
  const int bc = t - br * cb;
  const float* src = in + ((size_t)e * R + (size_t)br * 64) * C + (size_t)bc * 64;
#pragma unroll
  for (int i = 0; i < 16; ++i) {
    int idx = i * 256 + threadIdx.x;
    int r = idx >> 6, c = idx & 63;
    tl[c][r] = (__bf16)src[(size_t)r * C + c];
  }
  __syncthreads();
  __bf16* dst = outp + ((size_t)e * C + (size_t)bc * 64) * R + (size_t)br * 64;
#pragma unroll
  for (int i = 0; i < 8; ++i) {
    int idx = i * 512 + threadIdx.x * 2;
    int c = idx >> 6, r = idx & 63;
    bf16x2 p;
    p[0] = tl[c][r];
    p[1] = tl[c][r + 1];
    *(bf16x2*)(dst + (size_t)c * R + r) = p;
  }
}

// ================= 160KB kernel: 64x64 wave tiles, chunk 256h ===============
// LDS: XS [128m][256d] swz 64K | HC [128m][256h] swz 64K | STG 2 x 16K slabs.
// Slab = [256 r][32 k] bf16, 64B rows, phys 16B-slot = s ^ ((r>>1)&3).
// 64 slabs: c=s>>4 chunk, t=s&15: t<8 -> Wfc^T d-step t; t>=8 -> Wproj^T
// h-step t-8. 8 waves = 4 row-quads (q) x 2 m-halves (wm); wave tile 64x64.
#define B_XS   0
#define B_HC   65536
#define B_STG  131072
#define STG_SZ 16384
#define LDS160 163840

__global__ __launch_bounds__(512, 1) void fused_mlp_160(
    const float* __restrict__ x, const __bf16* __restrict__ wfcT,
    const __bf16* __restrict__ wprojT, float* __restrict__ out) {
  extern __shared__ char smem[];
  const int tid  = threadIdx.x;
  const int lane = tid & 63;
  const int l15  = lane & 15;
  const int l4   = lane >> 4;   // 0..3
  const int w    = tid >> 6;    // wave 0..7
  const int wm   = w & 1;       // m-half
  const int q    = w >> 1;      // row-quad 0..3 (64 rows each)
  const int bid  = blockIdx.x;
  const int e    = bid >> 5;
  const int m0   = (bid & 31) << 7;

  // thread-constant pieces of addresses
  const int physA = l4 ^ ((l15 >> 1) & 3);                 // slab A-frag slot
  const int aBase = B_STG + q * 4096 + l15 * 64 + physA * 16;  // + buf*STG_SZ + f*1024
  const int mRow  = wm * 64 + l15;                         // m within block (frag base)
  const int m7    = l15 & 7;

  auto stage_slab = [&](int s) {
    const int buf = s & 1;
    const int c   = s >> 4;
    const int t   = s & 15;
    const __bf16* base;
    size_t rs;
    if (t < 8) {
      base = wfcT + (size_t)(e * HDIM + c * 256) * DDIM + t * 32;
      rs   = DDIM;
    } else {
      base = wprojT + (size_t)(e * DDIM) * HDIM + c * 256 + (t - 8) * 32;
      rs   = HDIM;
    }
#pragma unroll
    for (int i = 0; i < 2; ++i) {
      int o  = tid + i * 512;          // 16B slot 0..1023
      int r  = o >> 2;                 // 0..255
      int sl = (o & 3) ^ ((r >> 1) & 3);
      gld_lds16(base + (size_t)r * rs + sl * 8, &smem[B_STG + buf * STG_SZ + o * 16]);
    }
  };

  // ---- stage X tile [128][256] fp32 -> bf16 swizzled into XS (once) ----
  {
    const float* xb = x + ((size_t)(e * CAPN + m0)) * DDIM;
#pragma unroll
    for (int i = 0; i < 8; ++i) {
      int f2  = i * 512 + tid;
      int row = f2 >> 5;
      int s   = f2 & 31;
      const float4 a0 = *(const float4*)(xb + (size_t)row * DDIM + s * 8);
      const float4 a1 = *(const float4*)(xb + (size_t)row * DDIM + s * 8 + 4);
      bf16x8 v;
      v[0] = (__bf16)a0.x; v[1] = (__bf16)a0.y; v[2] = (__bf16)a0.z; v[3] = (__bf16)a0.w;
      v[4] = (__bf16)a1.x; v[5] = (__bf16)a1.y; v[6] = (__bf16)a1.z; v[7] = (__bf16)a1.w;
      int phys = (s & 24) | ((s & 7) ^ (row & 7));
      *(bf16x8*)(&smem[B_XS + row * 512 + phys * 16]) = v;
    }
  }

  stage_slab(0);
  stage_slab(1);

  f32x4 zero = 0.0f;
  f32x4 acc2[4][4];  // [fd][fm]: d = q*64+fd*16, m = wm*64+fm*16
#pragma unroll
  for (int a = 0; a < 4; ++a)
#pragma unroll
    for (int b = 0; b < 4; ++b) acc2[a][b] = zero;

  for (int c = 0; c < 4; ++c) {
    // ---- P1: acc1[256h x 128m], K=256 as 8 slabs of 32d ----
    f32x4 acc1[4][4];
#pragma unroll
    for (int a = 0; a < 4; ++a)
#pragma unroll
      for (int b = 0; b < 4; ++b) acc1[a][b] = zero;

#pragma unroll
    for (int ds = 0; ds < 8; ++ds) {
      const int sidx = c * 16 + ds;
      const int buf  = ds & 1;  // c*16 even
      SLAB_PRE(false);
      bf16x8 af[4], bx[4];
#pragma unroll
      for (int f = 0; f < 4; ++f)
        af[f] = *(const bf16x8*)(&smem[aBase + buf * STG_SZ + f * 1024]);
#pragma unroll
      for (int fm = 0; fm < 4; ++fm) {
        int s  = ds * 4 + l4;
        int ph = (s & 24) | ((s & 7) ^ m7);
        bx[fm] = *(const bf16x8*)(&smem[B_XS + (mRow + fm * 16) * 512 + ph * 16]);
      }
      __builtin_amdgcn_s_setprio(1);
#pragma unroll
      for (int fa = 0; fa < 4; ++fa)
#pragma unroll
        for (int fm = 0; fm < 4; ++fm)
          acc1[fa][fm] = __builtin_amdgcn_mfma_f32_16x16x32_bf16(
              af[fa], bx[fm], acc1[fa][fm], 0, 0, 0);
      __builtin_amdgcn_s_setprio(0);
      SLAB_POST_160(sidx);
    }

    // ---- GELU -> HC [128m][256h] bf16 swizzled ----
#pragma unroll
    for (int fa = 0; fa < 4; ++fa) {
#pragma unroll
      for (int fm = 0; fm < 4; ++fm) {
        int m  = mRow + fm * 16;
        int s  = q * 8 + fa * 2 + (l4 >> 1);
        int hf = l4 & 1;
        bf16x4 hv;
#pragma unroll
        for (int j = 0; j < 4; ++j) hv[j] = (__bf16)gelu_f(acc1[fa][fm][j]);
        int ph = (s & 24) | ((s & 7) ^ (m & 7));
        *(bf16x4*)(&smem[B_HC + m * 512 + ph * 16 + hf * 8]) = hv;
      }
    }

    // ---- P2: acc2 += Wproj^T[256d x 32h] @ HC, 8 slabs of 32h ----
#pragma unroll
    for (int hs = 0; hs < 8; ++hs) {
      const int sidx = c * 16 + 8 + hs;
      const int buf  = hs & 1;  // (c*16+8+hs)&1 = hs&1
      const bool last = (hs == 7) && (c == 3);
      SLAB_PRE(last);
      bf16x8 af[4], bx[4];
#pragma unroll
      for (int f = 0; f < 4; ++f)
        af[f] = *(const bf16x8*)(&smem[aBase + buf * STG_SZ + f * 1024]);
#pragma unroll
      for (int fm = 0; fm < 4; ++fm) {
        int s  = hs * 4 + l4;
        int ph = (s & 24) | ((s & 7) ^ m7);
        bx[fm] = *(const bf16x8*)(&smem[B_HC + (mRow + fm * 16) * 512 + ph * 16]);
      }
      __builtin_amdgcn_s_setprio(1);
#pragma unroll
      for (int fd = 0; fd < 4; ++fd)
#pragma unroll
        for (int fm = 0; fm < 4; ++fm)
          acc2[fd][fm] = __builtin_amdgcn_mfma_f32_16x16x32_bf16(
              af[fd], bx[fm], acc2[fd][fm], 0, 0, 0);
      __builtin_amdgcn_s_setprio(0);
      SLAB_POST_160(sidx);
    }
  }

  // ---- epilogue ----
#pragma unroll
  for (int fd = 0; fd < 4; ++fd) {
#pragma unroll
    for (int fm = 0; fm < 4; ++fm) {
      int m = m0 + mRow + fm * 16;
      int d = q * 64 + fd * 16 + l4 * 4;
      *(f32x4*)(out + ((size_t)(e * CAPN + m)) * DDIM + d) = acc2[fd][fm];
    }
  }
}

// ================= 128KB fallback (round-2 kernel, verified 243us) ==========
#define F_XS   0
#define F_STG  65536
#define F_SSZ  16384
#define F_HC   98304
#define LDS128 131072

__global__ __launch_bounds__(512, 2) void fused_mlp_128(
    const float* __restrict__ x, const __bf16* __restrict__ wfcT,
    const __bf16* __restrict__ wprojT, float* __restrict__ out) {
  extern __shared__ char smem[];
  const int tid  = threadIdx.x;
  const int lane = tid & 63;
  const int l15  = lane & 15;
  const int l4   = lane >> 4;
  const int w    = tid >> 6;
  const int wm   = w & 1;
  const int q    = w >> 1;
  const int bid  = blockIdx.x;
  const int e    = bid >> 5;
  const int m0   = (bid & 31) << 7;

  auto stage_slab = [&](int s) {
    const int buf = s & 1;
    const int c   = s >> 3;
    const int t   = s & 7;
    const __bf16* base;
    size_t rs;
    if (t < 4) {
      base = wfcT + (size_t)(e * HDIM + c * 128) * DDIM + t * 64;
      rs   = DDIM;
    } else {
      const int j = t - 4;
      base = wprojT + (size_t)(e * DDIM + (j & 1) * 128) * HDIM + c * 128 + (j >> 1) * 64;
      rs   = HDIM;
    }
#pragma unroll
    for (int i = 0; i < 2; ++i) {
      int o  = tid + i * 512;
      int r  = o >> 3;
      int sl = (o & 7) ^ (r & 7);
      gld_lds16(base + (size_t)r * rs + sl * 8, &smem[F_STG + buf * F_SSZ + o * 16]);
    }
  };

  {
    const float* xb = x + ((size_t)(e * CAPN + m0)) * DDIM;
#pragma unroll
    for (int i = 0; i < 8; ++i) {
      int f2  = i * 512 + tid;
      int row = f2 >> 5;
      int s   = f2 & 31;
      const float4 a0 = *(const float4*)(xb + (size_t)row * DDIM + s * 8);
      const float4 a1 = *(const float4*)(xb + (size_t)row * DDIM + s * 8 + 4);
      bf16x8 v;
      v[0] = (__bf16)a0.x; v[1] = (__bf16)a0.y; v[2] = (__bf16)a0.z; v[3] = (__bf16)a0.w;
      v[4] = (__bf16)a1.x; v[5] = (__bf16)a1.y; v[6] = (__bf16)a1.z; v[7] = (__bf16)a1.w;
      int phys = (s & 24) | ((s & 7) ^ (row & 7));
      *(bf16x8*)(&smem[F_XS + row * 512 + phys * 16]) = v;
    }
  }

  stage_slab(0);
  stage_slab(1);

  f32x4 zero = 0.0f;
  f32x4 acc2[4][4];
#pragma unroll
  for (int a = 0; a < 4; ++a)
#pragma unroll
    for (int b = 0; b < 4; ++b) acc2[a][b] = zero;

  for (int c = 0; c < 8; ++c) {
    f32x4 acc1[2][4];
#pragma unroll
    for (int a = 0; a < 2; ++a)
#pragma unroll
      for (int b = 0; b < 4; ++b) acc1[a][b] = zero;

#pragma unroll
    for (int ks = 0; ks < 4; ++ks) {
      const int sidx = c * 8 + ks;
      const int buf  = sidx & 1;
      SLAB_PRE(false);
      bf16x8 a0[2], a1[2], b0[4], b1[4];
#pragma unroll
      for (int fh = 0; fh < 2; ++fh) {
        int r = q * 32 + fh * 16 + l15;
        a0[fh] = *(const bf16x8*)(&smem[F_STG + buf * F_SSZ + r * 128 + ((0 * 4 + l4) ^ (r & 7)) * 16]);
        a1[fh] = *(const bf16x8*)(&smem[F_STG + buf * F_SSZ + r * 128 + ((1 * 4 + l4) ^ (r & 7)) * 16]);
      }
#pragma unroll
      for (int fm = 0; fm < 4; ++fm) {
        int m   = wm * 64 + fm * 16 + l15;
        int sl0 = ks * 8 + 0 * 4 + l4;
        int sl1 = ks * 8 + 1 * 4 + l4;
        int p0  = (sl0 & 24) | ((sl0 & 7) ^ (m & 7));
        int p1  = (sl1 & 24) | ((sl1 & 7) ^ (m & 7));
        b0[fm] = *(const bf16x8*)(&smem[F_XS + m * 512 + p0 * 16]);
        b1[fm] = *(const bf16x8*)(&smem[F_XS + m * 512 + p1 * 16]);
      }
      __builtin_amdgcn_s_setprio(1);
#pragma unroll
      for (int fh = 0; fh < 2; ++fh)
#pragma unroll
        for (int fm = 0; fm < 4; ++fm)
          acc1[fh][fm] = __builtin_amdgcn_mfma_f32_16x16x32_bf16(a0[fh], b0[fm], acc1[fh][fm], 0, 0, 0);
#pragma unroll
      for (int fh = 0; fh < 2; ++fh)
#pragma unroll
        for (int fm = 0; fm < 4; ++fm)
          acc1[fh][fm] = __builtin_amdgcn_mfma_f32_16x16x32_bf16(a1[fh], b1[fm], acc1[fh][fm], 0, 0, 0);
      __builtin_amdgcn_s_setprio(0);
      SLAB_POST_128(sidx);
    }

#pragma unroll
    for (int fh = 0; fh < 2; ++fh) {
#pragma unroll
      for (int fm = 0; fm < 4; ++fm) {
        int m  = wm * 64 + fm * 16 + l15;
        int hl = q * 32 + fh * 16 + l4 * 4;
        bf16x4 hv;
#pragma unroll
        for (int j = 0; j < 4; ++j) hv[j] = (__bf16)gelu_f(acc1[fh][fm][j]);
        int sl   = hl >> 3;
        int half = (hl >> 2) & 1;
        int ph   = (sl & 8) | ((sl & 7) ^ (m & 7));
        *(bf16x4*)(&smem[F_HC + m * 256 + ph * 16 + half * 8]) = hv;
      }
    }

#pragma unroll
    for (int j = 0; j < 4; ++j) {
      const int sidx = c * 8 + 4 + j;
      const int buf  = sidx & 1;
      const int hd   = j & 1;
      const int hh   = j >> 1;
      const bool last = (c == 7) && (j == 3);
      SLAB_PRE(last);
      bf16x8 a0[2], a1[2], b0[4], b1[4];
#pragma unroll
      for (int fd = 0; fd < 2; ++fd) {
        int r = q * 32 + fd * 16 + l15;
        a0[fd] = *(const bf16x8*)(&smem[F_STG + buf * F_SSZ + r * 128 + ((0 * 4 + l4) ^ (r & 7)) * 16]);
        a1[fd] = *(const bf16x8*)(&smem[F_STG + buf * F_SSZ + r * 128 + ((1 * 4 + l4) ^ (r & 7)) * 16]);
      }
#pragma unroll
      for (int fm = 0; fm < 4; ++fm) {
        int m   = wm * 64 + fm * 16 + l15;
        int sl0 = hh * 8 + 0 * 4 + l4;
        int sl1 = hh * 8 + 1 * 4 + l4;
        int p0  = (sl0 & 8) | ((sl0 & 7) ^ (m & 7));
        int p1  = (sl1 & 8) | ((sl1 & 7) ^ (m & 7));
        b0[fm] = *(const bf16x8*)(&smem[F_HC + m * 256 + p0 * 16]);
        b1[fm] = *(const bf16x8*)(&smem[F_HC + m * 256 + p1 * 16]);
      }
      __builtin_amdgcn_s_setprio(1);
#pragma unroll
      for (int fd = 0; fd < 2; ++fd)
#pragma unroll
        for (int fm = 0; fm < 4; ++fm)
          acc2[hd * 2 + fd][fm] = __builtin_amdgcn_mfma_f32_16x16x32_bf16(a0[fd], b0[fm], acc2[hd * 2 + fd][fm], 0, 0, 0);
#pragma unroll
      for (int fd = 0; fd < 2; ++fd)
#pragma unroll
        for (int fm = 0; fm < 4; ++fm)
          acc2[hd * 2 + fd][fm] = __builtin_amdgcn_mfma_f32_16x16x32_bf16(a1[fd], b1[fm], acc2[hd * 2 + fd][fm], 0, 0, 0);
      __builtin_amdgcn_s_setprio(0);
      SLAB_POST_128(sidx);
    }
  }

#pragma unroll
  for (int a = 0; a < 4; ++a) {
#pragma unroll
    for (int fm = 0; fm < 4; ++fm) {
      int m = m0 + wm * 64 + fm * 16 + l15;
      int d = (a >> 1) * 128 + q * 32 + (a & 1) * 16 + l4 * 4;
      *(f32x4*)(out + ((size_t)(e * CAPN + m)) * DDIM + d) = acc2[a][fm];
    }
  }
}

extern "C" void kernel_launch(void* const* d_in, const int* in_sizes, int n_in,
                              void* d_out, int out_size, void* d_ws, size_t ws_size,
                              hipStream_t stream) {
  (void)in_sizes; (void)n_in; (void)out_size; (void)ws_size;
  const float* x     = (const float*)d_in[0];
  const float* wfc   = (const float*)d_in[1];   // [E][D][H]
  const float* wproj = (const float*)d_in[2];   // [E][H][D]
  float* out = (float*)d_out;

  __bf16* wfcT   = (__bf16*)d_ws;
  __bf16* wprojT = (__bf16*)((char*)d_ws + (size_t)NE * DDIM * HDIM * sizeof(__bf16));

  tcast_kernel<<<dim3(NE * 64), dim3(256), 0, stream>>>(wfc, wfcT, DDIM, HDIM);
  tcast_kernel<<<dim3(NE * 64), dim3(256), 0, stream>>>(wproj, wprojT, HDIM, DDIM);

  hipError_t e160 = hipFuncSetAttribute(
      (const void*)fused_mlp_160, hipFuncAttributeMaxDynamicSharedMemorySize, LDS160);
  if (e160 == hipSuccess) {
    fused_mlp_160<<<dim3(NE * 32), dim3(512), LDS160, stream>>>(x, wfcT, wprojT, out);
  } else {
    hipFuncSetAttribute((const void*)fused_mlp_128,
                        hipFuncAttributeMaxDynamicSharedMemorySize, LDS128);
    fused_mlp_128<<<dim3(NE * 32), dim3(512), LDS128, stream>>>(x, wfcT, wprojT, out);
  }
}

// Round 4
// 221.240 us; speedup vs baseline: 1.2620x; 1.0308x over previous
//
#include <hip/hip_runtime.h>
#include <cstdint>
#include <cstddef>

// ExpertMLP fused: out[e] = gelu(x[e] @ wfc[e]) @ wproj[e]
// E=32, CAP=4096, D=256, H=1024. fp32 in/out, bf16 MFMA internally.
// Round 4: single barrier per slab, 4 stage buffers / prefetch distance 3
// (counted vmcnt(4)), HC halved to 32KB via two-phase GELU, X-tile staged as
// 8 pipelined k-strips overlapped with chunk-0 P1. 160KB LDS, 1 block/CU.

#define NE   32
#define CAPN 4096
#define DDIM 256
#define HDIM 1024

typedef __bf16 bf16x8 __attribute__((ext_vector_type(8)));
typedef __bf16 bf16x4 __attribute__((ext_vector_type(4)));
typedef __bf16 bf16x2 __attribute__((ext_vector_type(2)));
typedef float  f32x4  __attribute__((ext_vector_type(4)));

// LDS map (160 KB):
//   XS : 8 strips x 8KB: [strip ds][128 m][4 slots16B], slot^=((m>>1)&3)
//   HC : [128 m][16 slots16B], 32KB, reused for each 128-h half
//   STG: 4 x 16KB slabs: [256 r][4 slots16B], slot^=((r>>1)&3)
#define B_XS   0
#define B_HC   65536
#define B_STG  98304
#define LDS160 163840

#define AS1 __attribute__((address_space(1)))
#define AS3 __attribute__((address_space(3)))

__device__ __forceinline__ void gld_lds16(const void* g, void* l) {
  __builtin_amdgcn_global_load_lds((const AS1 uint32_t*)g, (AS3 uint32_t*)l, 16, 0, 0);
}

// tanh-form GELU via exp2; |err vs erf-GELU| <~3e-3, NaN-free.
__device__ __forceinline__ float gelu_f(float x) {
  float x2 = x * x;
  float u  = x * __builtin_fmaf(0.1029432f, x2, 2.3022078f);
  float t  = __builtin_amdgcn_exp2f(u);
  float r  = __builtin_amdgcn_rcpf(t + 1.0f);
  return __builtin_fmaf(-x, r, x);
}

#define WAITV(n) asm volatile("s_waitcnt vmcnt(" #n ") lgkmcnt(0)" ::: "memory")
#define LGKM0()  asm volatile("s_waitcnt lgkmcnt(0)" ::: "memory")
#define BAR()    do { __builtin_amdgcn_s_barrier(); __builtin_amdgcn_sched_barrier(0); } while (0)

// ---------------- pre-pass: transpose + cast fp32 -> bf16 -------------------
__global__ __launch_bounds__(256) void tcast_kernel(const float* __restrict__ in,
                                                    __bf16* __restrict__ outp,
                                                    int R, int C) {
  __shared__ __bf16 tl[64][72];
  const int cb = C >> 6;
  const int nb = (R >> 6) * cb;
  const int b  = blockIdx.x;
  const int e  = b / nb;
  const int t  = b - e * nb;
  const int br = t / cb;
  const int bc = t - br * cb;
  const float* src = in + ((size_t)e * R + (size_t)br * 64) * C + (size_t)bc * 64;
#pragma unroll
  for (int i = 0; i < 16; ++i) {
    int idx = i * 256 + threadIdx.x;
    int r = idx >> 6, c = idx & 63;
    tl[c][r] = (__bf16)src[(size_t)r * C + c];
  }
  __syncthreads();
  __bf16* dst = outp + ((size_t)e * C + (size_t)bc * 64) * R + (size_t)br * 64;
#pragma unroll
  for (int i = 0; i < 8; ++i) {
    int idx = i * 512 + threadIdx.x * 2;
    int c = idx >> 6, r = idx & 63;
    bf16x2 p;
    p[0] = tl[c][r];
    p[1] = tl[c][r + 1];
    *(bf16x2*)(dst + (size_t)c * R + r) = p;
  }
}

// ---------------- fused MLP kernel ------------------------------------------
// grid 1024 blocks x 512 threads. 64 slab-windows of 16 per chunk:
//   t 0..7  : P1, Wfc^T  [256 h-rows][32 d], d-step t
//   t 8..15 : P2, Wproj^T[256 d-rows][32 h], half g=(t>>2)&1, hs=t&3
// Wave (q,wm): rows {q*32+(f&1)*16+(f>>1)*128}, m = wm*64+fm*16.
__global__ __launch_bounds__(512, 1) void fused_mlp(
    const float* __restrict__ x, const __bf16* __restrict__ wfcT,
    const __bf16* __restrict__ wprojT, float* __restrict__ out) {
  extern __shared__ char smem[];
  const int tid  = threadIdx.x;
  const int lane = tid & 63;
  const int l15  = lane & 15;
  const int l4   = lane >> 4;
  const int l7   = l15 & 7;
  const int w    = tid >> 6;
  const int wm   = w & 1;
  const int q    = w >> 1;
  const int e    = blockIdx.x >> 5;
  const int m0   = (blockIdx.x & 31) << 7;

  const int physA  = l4 ^ ((l15 >> 1) & 3);
  const int aOff0  = (q * 32 + l15) * 64 + physA * 16;  // +1024*(f&1) +8192*(f>>1)
  const int mRow   = wm * 64 + l15;
  const int bxOff0 = mRow * 64 + physA * 16;            // + fm*1024 within strip
  const int hcOff0 = mRow * 256;                        // + fm*4096 + p*16
  const int pl     = l4 ^ l7;

  const float* xbase = x + ((size_t)(e * CAPN + m0)) * DDIM;
  const int xm    = tid >> 2;
  const int xsl   = tid & 3;
  const int xphys = xsl ^ ((xm >> 1) & 3);

  auto stage_slab = [&](int s) {
    const int buf = s & 3;
    const int c   = s >> 4;
    const int t   = s & 15;
    const __bf16* base;
    size_t rs;
    if (t < 8) {
      base = wfcT + ((size_t)(e * HDIM + c * 256)) * DDIM + t * 32;
      rs   = DDIM;
    } else {
      base = wprojT + ((size_t)(e * DDIM)) * HDIM + c * 256 + ((t >> 2) & 1) * 128 + (t & 3) * 32;
      rs   = HDIM;
    }
#pragma unroll
    for (int i = 0; i < 2; ++i) {
      int o  = tid + i * 512;            // 16B slot 0..1023
      int r  = o >> 2;                   // 0..255
      int sl = (o & 3) ^ ((r >> 1) & 3); // swizzle via global source addr
      gld_lds16(base + (size_t)r * rs + sl * 8, &smem[B_STG + buf * 16384 + o * 16]);
    }
  };

  float4 xb0_[8], xb1_[8];  // X strip staging regs (compile-time indexed)

#define XLOAD(P) do {                                                          \
    const float* xs_ = xbase + (size_t)xm * DDIM + (P) * 32 + xsl * 8;         \
    xb0_[P] = *(const float4*)xs_;                                             \
    xb1_[P] = *(const float4*)(xs_ + 4);                                       \
  } while (0)

#define XCONV(P) do {                                                          \
    bf16x8 v_;                                                                 \
    v_[0] = (__bf16)xb0_[P].x; v_[1] = (__bf16)xb0_[P].y;                      \
    v_[2] = (__bf16)xb0_[P].z; v_[3] = (__bf16)xb0_[P].w;                      \
    v_[4] = (__bf16)xb1_[P].x; v_[5] = (__bf16)xb1_[P].y;                      \
    v_[6] = (__bf16)xb1_[P].z; v_[7] = (__bf16)xb1_[P].w;                      \
    *(bf16x8*)(&smem[B_XS + (P) * 8192 + xm * 64 + xphys * 16]) = v_;          \
  } while (0)

  f32x4 zero = 0.0f;
  f32x4 acc1[4][4], acc2[4][4];
#pragma unroll
  for (int a = 0; a < 4; ++a)
#pragma unroll
    for (int b = 0; b < 4; ++b) acc2[a][b] = zero;

#define ZERO_ACC1() do {                                                       \
    _Pragma("unroll") for (int a_ = 0; a_ < 4; ++a_)                           \
      _Pragma("unroll") for (int b_ = 0; b_ < 4; ++b_) acc1[a_][b_] = zero;    \
  } while (0)

#define P1SLAB(BUF, DS) do {                                                   \
    bf16x8 af_[4], bx_[4];                                                     \
    const char* sb_ = &smem[B_STG + (BUF) * 16384];                            \
    _Pragma("unroll") for (int f_ = 0; f_ < 4; ++f_)                           \
      af_[f_] = *(const bf16x8*)(sb_ + aOff0 + (f_ & 1) * 1024 + (f_ >> 1) * 8192); \
    const char* xs_ = &smem[B_XS + (DS) * 8192 + bxOff0];                      \
    _Pragma("unroll") for (int fm_ = 0; fm_ < 4; ++fm_)                        \
      bx_[fm_] = *(const bf16x8*)(xs_ + fm_ * 1024);                           \
    __builtin_amdgcn_s_setprio(1);                                             \
    _Pragma("unroll") for (int f_ = 0; f_ < 4; ++f_)                           \
      _Pragma("unroll") for (int fm_ = 0; fm_ < 4; ++fm_)                      \
        acc1[f_][fm_] = __builtin_amdgcn_mfma_f32_16x16x32_bf16(af_[f_], bx_[fm_], acc1[f_][fm_], 0, 0, 0); \
    __builtin_amdgcn_s_setprio(0);                                             \
  } while (0)

#define P2SLAB(BUF, HS) do {                                                   \
    bf16x8 af_[4], bx_[4];                                                     \
    const char* sb_ = &smem[B_STG + (BUF) * 16384];                            \
    _Pragma("unroll") for (int f_ = 0; f_ < 4; ++f_)                           \
      af_[f_] = *(const bf16x8*)(sb_ + aOff0 + (f_ & 1) * 1024 + (f_ >> 1) * 8192); \
    const int p_ = ((((HS) & 2) ? 8 : 0)) | (pl ^ (((HS) & 1) * 4));           \
    _Pragma("unroll") for (int fm_ = 0; fm_ < 4; ++fm_)                        \
      bx_[fm_] = *(const bf16x8*)(&smem[B_HC + hcOff0 + fm_ * 4096 + p_ * 16]); \
    __builtin_amdgcn_s_setprio(1);                                             \
    _Pragma("unroll") for (int f_ = 0; f_ < 4; ++f_)                           \
      _Pragma("unroll") for (int fm_ = 0; fm_ < 4; ++fm_)                      \
        acc2[f_][fm_] = __builtin_amdgcn_mfma_f32_16x16x32_bf16(af_[f_], bx_[fm_], acc2[f_][fm_], 0, 0, 0); \
    __builtin_amdgcn_s_setprio(0);                                             \
  } while (0)

#define GELU_HALF(G) do {                                                      \
    _Pragma("unroll") for (int f2_ = 0; f2_ < 2; ++f2_) {                      \
      const int s_ = q * 4 + f2_ * 2 + (l4 >> 1);                              \
      const int p_ = (s_ & 8) | ((s_ & 7) ^ l7);                               \
      _Pragma("unroll") for (int fm_ = 0; fm_ < 4; ++fm_) {                    \
        bf16x4 hv_;                                                            \
        _Pragma("unroll") for (int j_ = 0; j_ < 4; ++j_)                       \
          hv_[j_] = (__bf16)gelu_f(acc1[(G) * 2 + f2_][fm_][j_]);              \
        *(bf16x4*)(&smem[B_HC + hcOff0 + fm_ * 4096 + p_ * 16 + (l4 & 1) * 8]) = hv_; \
      }                                                                        \
    }                                                                          \
  } while (0)

  // windows ---------------------------------------------------------------
#define W_C0(T, VM) do {                                                       \
    WAITV(VM); BAR();                                                          \
    stage_slab((T) + 3);                                                       \
    if ((T) <= 4) XLOAD((T) + 3);                                              \
    P1SLAB((T) & 3, (T));                                                      \
    if ((T) <= 6) XCONV((T) + 1);                                              \
  } while (0)

#define W_P1(C, T) do {                                                        \
    WAITV(4); BAR();                                                           \
    stage_slab((C) * 16 + (T) + 3);                                            \
    P1SLAB((T) & 3, (T));                                                      \
  } while (0)

#define W_P2(C, T, VM) do {                                                    \
    WAITV(VM); BAR();                                                          \
    if ((C) * 16 + (T) + 3 < 64) stage_slab((C) * 16 + (T) + 3);               \
    P2SLAB((T) & 3, ((T) - 8) & 3);                                            \
  } while (0)

#define W_P2G(C) do { /* t=12: rewrite HC with half 1 under double barrier */  \
    WAITV(4); BAR();                                                           \
    stage_slab((C) * 16 + 15);                                                 \
    GELU_HALF(1);                                                              \
    LGKM0(); BAR();                                                            \
    P2SLAB(0, 0);                                                              \
  } while (0)

#define CHUNK_TAIL(C, VM14, VM15) do {                                         \
    GELU_HALF(0);                                                              \
    W_P2((C), 8, 4); W_P2((C), 9, 4); W_P2((C), 10, 4); W_P2((C), 11, 4);      \
    W_P2G(C);                                                                  \
    W_P2((C), 13, 4); W_P2((C), 14, VM14); W_P2((C), 15, VM15);                \
  } while (0)

  // prologue: 3 X strips + 3 weight slabs in flight, convert strip 0
  XLOAD(0); XLOAD(1); XLOAD(2);
  stage_slab(0); stage_slab(1); stage_slab(2);
  XCONV(0);

  // chunk 0 (X strips pipelined into P1)
  ZERO_ACC1();
  W_C0(0, 4); W_C0(1, 6); W_C0(2, 8); W_C0(3, 10);
  W_C0(4, 10); W_C0(5, 10); W_C0(6, 8); W_C0(7, 6);
  CHUNK_TAIL(0, 4, 4);

  // chunks 1..2
  for (int c = 1; c < 3; ++c) {
    ZERO_ACC1();
    W_P1(c, 0); W_P1(c, 1); W_P1(c, 2); W_P1(c, 3);
    W_P1(c, 4); W_P1(c, 5); W_P1(c, 6); W_P1(c, 7);
    CHUNK_TAIL(c, 4, 4);
  }

  // chunk 3 (stage stream drains: vmcnt 4,2,0 on the last windows)
  ZERO_ACC1();
  W_P1(3, 0); W_P1(3, 1); W_P1(3, 2); W_P1(3, 3);
  W_P1(3, 4); W_P1(3, 5); W_P1(3, 6); W_P1(3, 7);
  CHUNK_TAIL(3, 2, 0);

  // epilogue: acc2[f][fm] -> out[e][m0+m][d], d = q*32+(f&1)*16+(f>>1)*128+l4*4
#pragma unroll
  for (int f = 0; f < 4; ++f) {
#pragma unroll
    for (int fm = 0; fm < 4; ++fm) {
      int m = m0 + mRow + fm * 16;
      int d = q * 32 + (f & 1) * 16 + (f >> 1) * 128 + l4 * 4;
      *(f32x4*)(out + ((size_t)(e * CAPN + m)) * DDIM + d) = acc2[f][fm];
    }
  }
}

extern "C" void kernel_launch(void* const* d_in, const int* in_sizes, int n_in,
                              void* d_out, int out_size, void* d_ws, size_t ws_size,
                              hipStream_t stream) {
  (void)in_sizes; (void)n_in; (void)out_size; (void)ws_size;
  const float* x     = (const float*)d_in[0];
  const float* wfc   = (const float*)d_in[1];   // [E][D][H]
  const float* wproj = (const float*)d_in[2];   // [E][H][D]
  float* out = (float*)d_out;

  __bf16* wfcT   = (__bf16*)d_ws;
  __bf16* wprojT = (__bf16*)((char*)d_ws + (size_t)NE * DDIM * HDIM * sizeof(__bf16));

  hipFuncSetAttribute((const void*)fused_mlp,
                      hipFuncAttributeMaxDynamicSharedMemorySize, LDS160);

  tcast_kernel<<<dim3(NE * 64), dim3(256), 0, stream>>>(wfc, wfcT, DDIM, HDIM);
  tcast_kernel<<<dim3(NE * 64), dim3(256), 0, stream>>>(wproj, wprojT, HDIM, DDIM);
  fused_mlp<<<dim3(NE * 32), dim3(512), LDS160, stream>>>(x, wfcT, wprojT, out);
}

// Round 5
// 216.454 us; speedup vs baseline: 1.2899x; 1.0221x over previous
//
#include <hip/hip_runtime.h>
#include <cstdint>
#include <cstddef>

// ExpertMLP fused: out[e] = gelu(x[e] @ wfc[e]) @ wproj[e]
// E=32, CAP=4096, D=256, H=1024. fp32 in/out, bf16 MFMA internally.
// Round 5: operand PRE-READ double-buffering — window i's MFMA uses regs
// ds_read during window i-1 (in MFMA's shadow); WAITV(2)+lgkm0 BEFORE the
// barrier collectivizes "slab i+1 staged & reads drained". One barrier per
// window except the 2 GELU boundaries per chunk. 160KB LDS, 1 block/CU.

#define NE   32
#define CAPN 4096
#define DDIM 256
#define HDIM 1024

typedef __bf16 bf16x8 __attribute__((ext_vector_type(8)));
typedef __bf16 bf16x4 __attribute__((ext_vector_type(4)));
typedef __bf16 bf16x2 __attribute__((ext_vector_type(2)));
typedef float  f32x4  __attribute__((ext_vector_type(4)));

// LDS map (160 KB):
//   XS : 8 strips x 8KB: [strip ds][128 m][4 slots16B], slot^=((m>>1)&3)
//   HC : [128 m][16 slots16B], 32KB, reused per 128-h half
//   STG: 4 x 16KB slabs: [256 r][4 slots16B], slot^=((r>>1)&3)
#define B_XS   0
#define B_HC   65536
#define B_STG  98304
#define LDS160 163840

#define AS1 __attribute__((address_space(1)))
#define AS3 __attribute__((address_space(3)))

__device__ __forceinline__ void gld_lds16(const void* g, void* l) {
  __builtin_amdgcn_global_load_lds((const AS1 uint32_t*)g, (AS3 uint32_t*)l, 16, 0, 0);
}

// tanh-form GELU via exp2; |err vs erf-GELU| <~3e-3, NaN-free.
__device__ __forceinline__ float gelu_f(float x) {
  float x2 = x * x;
  float u  = x * __builtin_fmaf(0.1029432f, x2, 2.3022078f);
  float t  = __builtin_amdgcn_exp2f(u);
  float r  = __builtin_amdgcn_rcpf(t + 1.0f);
  return __builtin_fmaf(-x, r, x);
}

#define WAITV(n) asm volatile("s_waitcnt vmcnt(" #n ") lgkmcnt(0)" ::: "memory")
#define LGKM0()  asm volatile("s_waitcnt lgkmcnt(0)" ::: "memory")
#define BAR()    do { __builtin_amdgcn_s_barrier(); __builtin_amdgcn_sched_barrier(0); } while (0)
#define SB0()    __builtin_amdgcn_sched_barrier(0)

// ---------------- pre-pass: transpose + cast fp32 -> bf16 -------------------
__global__ __launch_bounds__(256) void tcast_kernel(const float* __restrict__ in,
                                                    __bf16* __restrict__ outp,
                                                    int R, int C) {
  __shared__ __bf16 tl[64][72];
  const int cb = C >> 6;
  const int nb = (R >> 6) * cb;
  const int b  = blockIdx.x;
  const int e  = b / nb;
  const int t  = b - e * nb;
  const int br = t / cb;
  const int bc = t - br * cb;
  const float* src = in + ((size_t)e * R + (size_t)br * 64) * C + (size_t)bc * 64;
#pragma unroll
  for (int i = 0; i < 16; ++i) {
    int idx = i * 256 + threadIdx.x;
    int r = idx >> 6, c = idx & 63;
    tl[c][r] = (__bf16)src[(size_t)r * C + c];
  }
  __syncthreads();
  __bf16* dst = outp + ((size_t)e * C + (size_t)bc * 64) * R + (size_t)br * 64;
#pragma unroll
  for (int i = 0; i < 8; ++i) {
    int idx = i * 512 + threadIdx.x * 2;
    int c = idx >> 6, r = idx & 63;
    bf16x2 p;
    p[0] = tl[c][r];
    p[1] = tl[c][r + 1];
    *(bf16x2*)(dst + (size_t)c * R + r) = p;
  }
}

// ---------------- fused MLP kernel ------------------------------------------
// grid 1024 blocks x 512 threads. 64 windows/block, window t of chunk c:
//   t 0..7  : P1, Wfc^T  [256 h-rows][32 d], d-step t
//   t 8..15 : P2, Wproj^T[256 d-rows][32 h], half (t>=12), hs=t&3
// Wave (q,wm): rows {q*32+(f&1)*16+(f>>1)*128}, m = wm*64+fm*16.
__global__ __launch_bounds__(512, 1) void fused_mlp(
    const float* __restrict__ x, const __bf16* __restrict__ wfcT,
    const __bf16* __restrict__ wprojT, float* __restrict__ out) {
  extern __shared__ char smem[];
  const int tid  = threadIdx.x;
  const int lane = tid & 63;
  const int l15  = lane & 15;
  const int l4   = lane >> 4;
  const int l7   = l15 & 7;
  const int w    = tid >> 6;
  const int wm   = w & 1;
  const int q    = w >> 1;
  const int e    = blockIdx.x >> 5;
  const int m0   = (blockIdx.x & 31) << 7;

  const int physA  = l4 ^ ((l15 >> 1) & 3);
  const int aOff0  = (q * 32 + l15) * 64 + physA * 16;  // +1024*(f&1) +8192*(f>>1)
  const int mRow   = wm * 64 + l15;
  const int bxOff0 = mRow * 64 + physA * 16;            // + fm*1024 within strip
  const int hcOff0 = mRow * 256;                        // + fm*4096 + p*16
  const int pl     = l4 ^ l7;

  const float* xbase = x + ((size_t)(e * CAPN + m0)) * DDIM;
  const int xm    = tid >> 2;
  const int xsl   = tid & 3;
  const int xphys = xsl ^ ((xm >> 1) & 3);

  auto stage_slab = [&](int s) {
    const int buf = s & 3;
    const int c   = s >> 4;
    const int t   = s & 15;
    const __bf16* base;
    size_t rs;
    if (t < 8) {
      base = wfcT + ((size_t)(e * HDIM + c * 256)) * DDIM + t * 32;
      rs   = DDIM;
    } else {
      base = wprojT + ((size_t)(e * DDIM)) * HDIM + c * 256 + ((t >> 2) & 1) * 128 + (t & 3) * 32;
      rs   = HDIM;
    }
#pragma unroll
    for (int i = 0; i < 2; ++i) {
      int o  = tid + i * 512;            // 16B slot 0..1023
      int r  = o >> 2;                   // 0..255
      int sl = (o & 3) ^ ((r >> 1) & 3); // swizzle via global source addr
      gld_lds16(base + (size_t)r * rs + sl * 8, &smem[B_STG + buf * 16384 + o * 16]);
    }
  };

  float4 xb0_[8], xb1_[8];  // X strip staging regs (static indices only)

#define XLOAD(P) do {                                                          \
    const float* xs_ = xbase + (size_t)xm * DDIM + (P) * 32 + xsl * 8;         \
    xb0_[P] = *(const float4*)xs_;                                             \
    xb1_[P] = *(const float4*)(xs_ + 4);                                       \
  } while (0)

#define XCONV(P) do {                                                          \
    bf16x8 v_;                                                                 \
    v_[0] = (__bf16)xb0_[P].x; v_[1] = (__bf16)xb0_[P].y;                      \
    v_[2] = (__bf16)xb0_[P].z; v_[3] = (__bf16)xb0_[P].w;                      \
    v_[4] = (__bf16)xb1_[P].x; v_[5] = (__bf16)xb1_[P].y;                      \
    v_[6] = (__bf16)xb1_[P].z; v_[7] = (__bf16)xb1_[P].w;                      \
    *(bf16x8*)(&smem[B_XS + (P) * 8192 + xm * 64 + xphys * 16]) = v_;          \
  } while (0)

  f32x4 zero = 0.0f;
  f32x4 acc1[4][4], acc2[4][4];
#pragma unroll
  for (int a = 0; a < 4; ++a)
#pragma unroll
    for (int b = 0; b < 4; ++b) acc2[a][b] = zero;

#define ZERO_ACC1() do {                                                       \
    _Pragma("unroll") for (int a_ = 0; a_ < 4; ++a_)                           \
      _Pragma("unroll") for (int b_ = 0; b_ < 4; ++b_) acc1[a_][b_] = zero;    \
  } while (0)

  // operand double-buffer: set A used by even windows, set B by odd windows.
  bf16x8 afA[4], bxA[4], afB[4], bxB[4];

#define PRE_AF(SET, BUF_) do {                                                 \
    const char* sb_ = &smem[B_STG + (BUF_) * 16384];                           \
    _Pragma("unroll") for (int f_ = 0; f_ < 4; ++f_)                           \
      af##SET[f_] = *(const bf16x8*)(sb_ + aOff0 + (f_ & 1) * 1024 + (f_ >> 1) * 8192); \
  } while (0)

#define PRE_BX1(SET, DS_) do {                                                 \
    const char* xs_ = &smem[B_XS + (DS_) * 8192 + bxOff0];                     \
    _Pragma("unroll") for (int fm_ = 0; fm_ < 4; ++fm_)                        \
      bx##SET[fm_] = *(const bf16x8*)(xs_ + fm_ * 1024);                       \
  } while (0)

#define PRE_BX2(SET, HS_) do {                                                 \
    const int p_ = (((HS_) & 2) ? 8 : 0) | (pl ^ (((HS_) & 1) * 4));           \
    _Pragma("unroll") for (int fm_ = 0; fm_ < 4; ++fm_)                        \
      bx##SET[fm_] = *(const bf16x8*)(&smem[B_HC + hcOff0 + fm_ * 4096 + p_ * 16]); \
  } while (0)

#define MFMA16(SET, ACC) do {                                                  \
    __builtin_amdgcn_s_setprio(1);                                             \
    _Pragma("unroll") for (int f_ = 0; f_ < 4; ++f_)                           \
      _Pragma("unroll") for (int fm_ = 0; fm_ < 4; ++fm_)                      \
        ACC[f_][fm_] = __builtin_amdgcn_mfma_f32_16x16x32_bf16(af##SET[f_], bx##SET[fm_], ACC[f_][fm_], 0, 0, 0); \
    __builtin_amdgcn_s_setprio(0);                                             \
  } while (0)

#define GELU_HALF(G) do {                                                      \
    _Pragma("unroll") for (int f2_ = 0; f2_ < 2; ++f2_) {                      \
      const int s_ = q * 4 + f2_ * 2 + (l4 >> 1);                              \
      const int p_ = (s_ & 8) | ((s_ & 7) ^ l7);                               \
      _Pragma("unroll") for (int fm_ = 0; fm_ < 4; ++fm_) {                    \
        bf16x4 hv_;                                                            \
        _Pragma("unroll") for (int j_ = 0; j_ < 4; ++j_)                       \
          hv_[j_] = (__bf16)gelu_f(acc1[(G) * 2 + f2_][fm_][j_]);              \
        *(bf16x4*)(&smem[B_HC + hcOff0 + fm_ * 4096 + p_ * 16 + (l4 & 1) * 8]) = hv_; \
      }                                                                        \
    }                                                                          \
  } while (0)

  // t=0..6 steady head (chunks >= 1)
#define CHUNK_HEAD(C_) do {                                                    \
    WAITV(2); BAR(); MFMA16(A, acc1); stage_slab((C_)*16 + 3);  PRE_AF(B, 1); PRE_BX1(B, 1); \
    WAITV(2); BAR(); MFMA16(B, acc1); stage_slab((C_)*16 + 4);  PRE_AF(A, 2); PRE_BX1(A, 2); \
    WAITV(2); BAR(); MFMA16(A, acc1); stage_slab((C_)*16 + 5);  PRE_AF(B, 3); PRE_BX1(B, 3); \
    WAITV(2); BAR(); MFMA16(B, acc1); stage_slab((C_)*16 + 6);  PRE_AF(A, 0); PRE_BX1(A, 4); \
    WAITV(2); BAR(); MFMA16(A, acc1); stage_slab((C_)*16 + 7);  PRE_AF(B, 1); PRE_BX1(B, 5); \
    WAITV(2); BAR(); MFMA16(B, acc1); stage_slab((C_)*16 + 8);  PRE_AF(A, 2); PRE_BX1(A, 6); \
    WAITV(2); BAR(); MFMA16(A, acc1); stage_slab((C_)*16 + 9);  PRE_AF(B, 3); PRE_BX1(B, 7); \
  } while (0)

  // t=7..15 (GELU0 at t7, late bx at t8/t12, GELU1 double-barrier at t12)
#define CHUNK_TAIL7(C_, LAST_) do {                                            \
    WAITV(2); BAR(); MFMA16(B, acc1); GELU_HALF(0);                            \
      stage_slab((C_)*16 + 10); PRE_AF(A, 0);                                  \
    WAITV(2); BAR(); PRE_BX2(A, 0); MFMA16(A, acc2);                           \
      stage_slab((C_)*16 + 11); PRE_AF(B, 1); PRE_BX2(B, 1);                   \
    WAITV(2); BAR(); MFMA16(B, acc2); stage_slab((C_)*16 + 12);                \
      PRE_AF(A, 2); PRE_BX2(A, 2);                                             \
    WAITV(2); BAR(); MFMA16(A, acc2); stage_slab((C_)*16 + 13);                \
      PRE_AF(B, 3); PRE_BX2(B, 3);                                             \
    WAITV(2); BAR(); MFMA16(B, acc2); stage_slab((C_)*16 + 14);                \
      PRE_AF(A, 0);                                                            \
    WAITV(2); BAR(); GELU_HALF(1); ZERO_ACC1(); LGKM0(); BAR();                \
      PRE_BX2(A, 0); MFMA16(A, acc2); stage_slab((C_)*16 + 15);                \
      PRE_AF(B, 1); PRE_BX2(B, 1);                                             \
    WAITV(2); BAR(); MFMA16(B, acc2);                                          \
      if (!(LAST_)) stage_slab((C_)*16 + 16);                                  \
      PRE_AF(A, 2); PRE_BX2(A, 2);                                             \
    if (LAST_) { WAITV(0); } else { WAITV(2); }                                \
    BAR(); MFMA16(A, acc2);                                                    \
      if (!(LAST_)) stage_slab((C_)*16 + 17);                                  \
      PRE_AF(B, 3); PRE_BX2(B, 3);                                             \
    if (LAST_) { WAITV(0); } else { WAITV(2); }                                \
    BAR(); MFMA16(B, acc2);                                                    \
      if (!(LAST_)) { stage_slab((C_)*16 + 18); PRE_AF(A, 0); PRE_BX1(A, 0); } \
  } while (0)

  // ---- prologue: X strips 0-2 + slabs 0-2 in flight; conv strips 0,1 ----
  ZERO_ACC1();
  XLOAD(0); XLOAD(1); XLOAD(2);
  SB0();
  stage_slab(0); stage_slab(1); stage_slab(2);
  XCONV(0); XCONV(1);

  // ---- chunk 0: X pipeline interleaved into P1 windows (queue-derived VM) --
  WAITV(2); BAR();
  PRE_AF(A, 0); PRE_BX1(A, 0);          // one-time direct read for slab 0
  MFMA16(A, acc1);
  stage_slab(3); SB0(); XLOAD(3); PRE_AF(B, 1); PRE_BX1(B, 1); XCONV(2);
  WAITV(4); BAR(); MFMA16(B, acc1);
  stage_slab(4); SB0(); XLOAD(4); PRE_AF(A, 2); PRE_BX1(A, 2); XCONV(3);
  WAITV(6); BAR(); MFMA16(A, acc1);
  stage_slab(5); SB0(); XLOAD(5); PRE_AF(B, 3); PRE_BX1(B, 3); XCONV(4);
  WAITV(6); BAR(); MFMA16(B, acc1);
  stage_slab(6); SB0(); XLOAD(6); PRE_AF(A, 0); PRE_BX1(A, 4); XCONV(5);
  WAITV(6); BAR(); MFMA16(A, acc1);
  stage_slab(7); SB0(); XLOAD(7); PRE_AF(B, 1); PRE_BX1(B, 5); XCONV(6);
  WAITV(6); BAR(); MFMA16(B, acc1);
  stage_slab(8); PRE_AF(A, 2); PRE_BX1(A, 6); XCONV(7);
  WAITV(4); BAR(); MFMA16(A, acc1);
  stage_slab(9); PRE_AF(B, 3); PRE_BX1(B, 7);
  CHUNK_TAIL7(0, 0);

  // ---- chunks 1..2 ----
  for (int c = 1; c < 3; ++c) {
    CHUNK_HEAD(c);
    CHUNK_TAIL7(c, 0);
  }

  // ---- chunk 3 (drain) ----
  CHUNK_HEAD(3);
  CHUNK_TAIL7(3, 1);

  // ---- epilogue: acc2[f][fm] -> out; d = q*32+(f&1)*16+(f>>1)*128+l4*4 ----
#pragma unroll
  for (int f = 0; f < 4; ++f) {
#pragma unroll
    for (int fm = 0; fm < 4; ++fm) {
      int m = m0 + mRow + fm * 16;
      int d = q * 32 + (f & 1) * 16 + (f >> 1) * 128 + l4 * 4;
      *(f32x4*)(out + ((size_t)(e * CAPN + m)) * DDIM + d) = acc2[f][fm];
    }
  }
}

extern "C" void kernel_launch(void* const* d_in, const int* in_sizes, int n_in,
                              void* d_out, int out_size, void* d_ws, size_t ws_size,
                              hipStream_t stream) {
  (void)in_sizes; (void)n_in; (void)out_size; (void)ws_size;
  const float* x     = (const float*)d_in[0];
  const float* wfc   = (const float*)d_in[1];   // [E][D][H]
  const float* wproj = (const float*)d_in[2];   // [E][H][D]
  float* out = (float*)d_out;

  __bf16* wfcT   = (__bf16*)d_ws;
  __bf16* wprojT = (__bf16*)((char*)d_ws + (size_t)NE * DDIM * HDIM * sizeof(__bf16));

  hipFuncSetAttribute((const void*)fused_mlp,
                      hipFuncAttributeMaxDynamicSharedMemorySize, LDS160);

  tcast_kernel<<<dim3(NE * 64), dim3(256), 0, stream>>>(wfc, wfcT, DDIM, HDIM);
  tcast_kernel<<<dim3(NE * 64), dim3(256), 0, stream>>>(wproj, wprojT, HDIM, DDIM);
  fused_mlp<<<dim3(NE * 32), dim3(512), LDS160, stream>>>(x, wfcT, wprojT, out);
}

// Round 6
// 210.148 us; speedup vs baseline: 1.3286x; 1.0300x over previous
//
#include <hip/hip_runtime.h>
#include <cstdint>
#include <cstddef>

// ExpertMLP fused: out[e] = gelu(x[e] @ wfc[e]) @ wproj[e]
// E=32, CAP=4096, D=256, H=1024. fp32 in/out, bf16 MFMA internally.
// Round 6: cross-barrier operand pre-reads (vmcnt-only steady wait; NO lgkm
// drain of pre-reads), compiler per-operand lgkm waits inside MFMA cluster,
// VALU-lean staging (precomputed lane offsets + literal window constants).

#define NE   32
#define CAPN 4096
#define DDIM 256
#define HDIM 1024

typedef __bf16 bf16x8 __attribute__((ext_vector_type(8)));
typedef __bf16 bf16x4 __attribute__((ext_vector_type(4)));
typedef __bf16 bf16x2 __attribute__((ext_vector_type(2)));
typedef float  f32x4  __attribute__((ext_vector_type(4)));

// LDS map (160 KB):
//   XS : 8 strips x 8KB: [strip ds][128 m][4 slots16B], slot^=((m>>1)&3)
//   HC : [128 m][16 slots16B], 32KB, reused per 128-h half
//   STG: 4 x 16KB slabs: [256 r][4 slots16B], slot^=((r>>1)&3)
#define B_XS   0
#define B_HC   65536
#define B_STG  98304
#define LDS160 163840

#define AS1 __attribute__((address_space(1)))
#define AS3 __attribute__((address_space(3)))

__device__ __forceinline__ void gld_lds16(const void* g, void* l) {
  __builtin_amdgcn_global_load_lds((const AS1 uint32_t*)g, (AS3 uint32_t*)l, 16, 0, 0);
}

// tanh-form GELU via exp2; |err vs erf-GELU| <~3e-3, NaN-free.
__device__ __forceinline__ float gelu_f(float x) {
  float x2 = x * x;
  float u  = x * __builtin_fmaf(0.1029432f, x2, 2.3022078f);
  float t  = __builtin_amdgcn_exp2f(u);
  float r  = __builtin_amdgcn_rcpf(t + 1.0f);
  return __builtin_fmaf(-x, r, x);
}

#define WV_(n)  asm volatile("s_waitcnt vmcnt(" #n ")" ::: "memory")
#define WV(n)   WV_(n)
#define WVL_(n) asm volatile("s_waitcnt vmcnt(" #n ") lgkmcnt(0)" ::: "memory")
#define WVL(n)  WVL_(n)
#define LGKM0() asm volatile("s_waitcnt lgkmcnt(0)" ::: "memory")
#define BAR()   do { __builtin_amdgcn_s_barrier(); __builtin_amdgcn_sched_barrier(0); } while (0)

// ---------------- pre-pass: transpose + cast fp32 -> bf16 -------------------
__global__ __launch_bounds__(256) void tcast_kernel(const float* __restrict__ in,
                                                    __bf16* __restrict__ outp,
                                                    int R, int C) {
  __shared__ __bf16 tl[64][72];
  const int cb = C >> 6;
  const int nb = (R >> 6) * cb;
  const int b  = blockIdx.x;
  const int e  = b / nb;
  const int t  = b - e * nb;
  const int br = t / cb;
  const int bc = t - br * cb;
  const float* src = in + ((size_t)e * R + (size_t)br * 64) * C + (size_t)bc * 64;
#pragma unroll
  for (int i = 0; i < 16; ++i) {
    int idx = i * 256 + threadIdx.x;
    int r = idx >> 6, c = idx & 63;
    tl[c][r] = (__bf16)src[(size_t)r * C + c];
  }
  __syncthreads();
  __bf16* dst = outp + ((size_t)e * C + (size_t)bc * 64) * R + (size_t)br * 64;
#pragma unroll
  for (int i = 0; i < 8; ++i) {
    int idx = i * 512 + threadIdx.x * 2;
    int c = idx >> 6, r = idx & 63;
    bf16x2 p;
    p[0] = tl[c][r];
    p[1] = tl[c][r + 1];
    *(bf16x2*)(dst + (size_t)c * R + r) = p;
  }
}

// ---------------- fused MLP kernel ------------------------------------------
__global__ __launch_bounds__(512, 1) void fused_mlp(
    const float* __restrict__ x, const __bf16* __restrict__ wfcT,
    const __bf16* __restrict__ wprojT, float* __restrict__ out) {
  extern __shared__ char smem[];
  const int tid  = threadIdx.x;
  const int lane = tid & 63;
  const int l15  = lane & 15;
  const int l4   = lane >> 4;
  const int l7   = l15 & 7;
  const int w    = tid >> 6;
  const int wm   = w & 1;
  const int q    = w >> 1;
  const int e    = blockIdx.x >> 5;
  const int m0   = (blockIdx.x & 31) << 7;

  const int physA  = l4 ^ ((l15 >> 1) & 3);
  const int aOff0  = (q * 32 + l15) * 64 + physA * 16;  // +1024*(f&1) +8192*(f>>1)
  const int mRow   = wm * 64 + l15;
  const int bxOff0 = mRow * 64 + physA * 16;            // + fm*1024 within strip
  const int hcOff0 = mRow * 256;                        // + fm*4096 + p*16
  const int pl     = l4 ^ l7;

  // stage lane offsets (elements): row rr, swizzled slot ssl; 2nd gld is +128 rows.
  const int rr  = tid >> 2;
  const int ssl = (tid & 3) ^ ((rr >> 1) & 3);
  const int gofsFC = rr * DDIM + ssl * 8;
  const int gofsPJ = rr * HDIM + ssl * 8;
  const __bf16* wfcT_e   = wfcT   + (size_t)e * HDIM * DDIM;
  const __bf16* wprojT_e = wprojT + (size_t)e * DDIM * HDIM;
  char* ldsStg0 = smem + B_STG + tid * 16;  // + buf*16384 ; second dest +8192

  const float* xbase = x + ((size_t)(e * CAPN + m0)) * DDIM;
  const int xm    = tid >> 2;
  const int xsl   = tid & 3;
  const int xphys = xsl ^ ((xm >> 1) & 3);

#define STAGE_FC(C_, T_) do {                                                  \
    const __bf16* s0_ = wfcT_e + (size_t)(C_) * (256 * DDIM) + (T_) * 32 + gofsFC; \
    gld_lds16(s0_,              ldsStg0 + ((T_) & 3) * 16384);                 \
    gld_lds16(s0_ + 128 * DDIM, ldsStg0 + ((T_) & 3) * 16384 + 8192);          \
  } while (0)

#define STAGE_PJ(C_, T_) do {                                                  \
    const __bf16* s0_ = wprojT_e + (size_t)(C_) * 256 +                        \
                        (((T_) >> 2) & 1) * 128 + ((T_) & 3) * 32 + gofsPJ;    \
    gld_lds16(s0_,              ldsStg0 + ((T_) & 3) * 16384);                 \
    gld_lds16(s0_ + 128 * HDIM, ldsStg0 + ((T_) & 3) * 16384 + 8192);          \
  } while (0)

  float4 xb0_[8], xb1_[8];  // X strip staging regs (static indices only)

#define XLOAD(P) do {                                                          \
    const float* xs_ = xbase + (size_t)xm * DDIM + (P) * 32 + xsl * 8;         \
    xb0_[P] = *(const float4*)xs_;                                             \
    xb1_[P] = *(const float4*)(xs_ + 4);                                       \
  } while (0)

#define XCONV(P) do {                                                          \
    bf16x8 v_;                                                                 \
    v_[0] = (__bf16)xb0_[P].x; v_[1] = (__bf16)xb0_[P].y;                      \
    v_[2] = (__bf16)xb0_[P].z; v_[3] = (__bf16)xb0_[P].w;                      \
    v_[4] = (__bf16)xb1_[P].x; v_[5] = (__bf16)xb1_[P].y;                      \
    v_[6] = (__bf16)xb1_[P].z; v_[7] = (__bf16)xb1_[P].w;                      \
    *(bf16x8*)(&smem[B_XS + (P) * 8192 + xm * 64 + xphys * 16]) = v_;          \
  } while (0)

  f32x4 zero = 0.0f;
  f32x4 acc1[4][4], acc2[4][4];
#pragma unroll
  for (int a = 0; a < 4; ++a)
#pragma unroll
    for (int b = 0; b < 4; ++b) { acc1[a][b] = zero; acc2[a][b] = zero; }

#define ZERO_ACC1() do {                                                       \
    _Pragma("unroll") for (int a_ = 0; a_ < 4; ++a_)                           \
      _Pragma("unroll") for (int b_ = 0; b_ < 4; ++b_) acc1[a_][b_] = zero;    \
  } while (0)

  // operand double-buffer: set 0 for even windows, set 1 for odd windows.
  bf16x8 afR0[4], bxR0[4], afR1[4], bxR1[4];

#define PAF(S_, BUF_) do {                                                     \
    const char* sb_ = smem + B_STG + (BUF_) * 16384;                           \
    _Pragma("unroll") for (int f_ = 0; f_ < 4; ++f_)                           \
      afR##S_[f_] = *(const bf16x8*)(sb_ + aOff0 + (f_ & 1) * 1024 + (f_ >> 1) * 8192); \
  } while (0)

#define PBX1(S_, DS_) do {                                                     \
    const char* xs_ = smem + B_XS + (DS_) * 8192 + bxOff0;                     \
    _Pragma("unroll") for (int fm_ = 0; fm_ < 4; ++fm_)                        \
      bxR##S_[fm_] = *(const bf16x8*)(xs_ + fm_ * 1024);                       \
  } while (0)

#define PBX2(S_, HS_) do {                                                     \
    const int p_ = ((((HS_) & 2) ? 8 : 0)) | (pl ^ (((HS_) & 1) * 4));         \
    _Pragma("unroll") for (int fm_ = 0; fm_ < 4; ++fm_)                        \
      bxR##S_[fm_] = *(const bf16x8*)(&smem[B_HC + hcOff0 + fm_ * 4096 + p_ * 16]); \
  } while (0)

#define MFMA16(S_, ACC_) do {                                                  \
    __builtin_amdgcn_s_setprio(1);                                             \
    _Pragma("unroll") for (int f_ = 0; f_ < 4; ++f_)                           \
      _Pragma("unroll") for (int fm_ = 0; fm_ < 4; ++fm_)                      \
        ACC_[f_][fm_] = __builtin_amdgcn_mfma_f32_16x16x32_bf16(afR##S_[f_], bxR##S_[fm_], ACC_[f_][fm_], 0, 0, 0); \
    __builtin_amdgcn_s_setprio(0);                                             \
  } while (0)

#define GELU_HALF(G) do {                                                      \
    _Pragma("unroll") for (int f2_ = 0; f2_ < 2; ++f2_) {                      \
      const int s_ = q * 4 + f2_ * 2 + (l4 >> 1);                              \
      const int p_ = (s_ & 8) | ((s_ & 7) ^ l7);                               \
      _Pragma("unroll") for (int fm_ = 0; fm_ < 4; ++fm_) {                    \
        bf16x4 hv_;                                                            \
        _Pragma("unroll") for (int j_ = 0; j_ < 4; ++j_)                       \
          hv_[j_] = (__bf16)gelu_f(acc1[(G) * 2 + f2_][fm_][j_]);              \
        *(bf16x4*)(&smem[B_HC + hcOff0 + fm_ * 4096 + p_ * 16 + (l4 & 1) * 8]) = hv_; \
      }                                                                        \
    }                                                                          \
  } while (0)

  // ---- prologue: X strips 0-2 + slabs 0-2 in flight; convert strips 0,1 ----
  XLOAD(0); XLOAD(1); XLOAD(2);
  STAGE_FC(0, 0); STAGE_FC(0, 1); STAGE_FC(0, 2);
  XCONV(0); XCONV(1);  // compiler inserts precise vmcnt waits for xb regs

  // ================= chunk 0 (X pipeline interleaved) =================
  WVL(2); BAR();
  PAF(0, 0); PBX1(0, 0);                    // one-time late read for slab 0
  MFMA16(0, acc1);
  XLOAD(3); STAGE_FC(0, 3); PAF(1, 1); PBX1(1, 1); XCONV(2);
  WVL(2); BAR(); MFMA16(1, acc1);
  XLOAD(4); STAGE_FC(0, 4); PAF(0, 2); PBX1(0, 2); XCONV(3);
  WVL(2); BAR(); MFMA16(0, acc1);
  XLOAD(5); STAGE_FC(0, 5); PAF(1, 3); PBX1(1, 3); XCONV(4);
  WVL(2); BAR(); MFMA16(1, acc1);
  XLOAD(6); STAGE_FC(0, 6); PAF(0, 0); PBX1(0, 4); XCONV(5);
  WVL(2); BAR(); MFMA16(0, acc1);
  XLOAD(7); STAGE_FC(0, 7); PAF(1, 1); PBX1(1, 5); XCONV(6);
  WVL(2); BAR(); MFMA16(1, acc1);
  STAGE_PJ(0, 8); PAF(0, 2); PBX1(0, 6); XCONV(7);
  WVL(2); BAR(); MFMA16(0, acc1);
  STAGE_PJ(0, 9); PAF(1, 3); PBX1(1, 7);
  WVL(2); BAR(); MFMA16(1, acc1);           // w7
  STAGE_PJ(0, 10); PAF(0, 0); GELU_HALF(0);

#define CHUNK_TAIL(C_) do {                                                    \
    WVL(2); BAR(); PBX2(0, 0); MFMA16(0, acc2);            /* w8  */           \
    STAGE_PJ(C_, 11); PAF(1, 1); PBX2(1, 1);                                   \
    WV(2); BAR(); MFMA16(1, acc2);                         /* w9  */           \
    STAGE_PJ(C_, 12); PAF(0, 2); PBX2(0, 2);                                   \
    WV(2); BAR(); MFMA16(0, acc2);                         /* w10 */           \
    STAGE_PJ(C_, 13); PAF(1, 3); PBX2(1, 3);                                   \
    WV(2); BAR(); MFMA16(1, acc2);                         /* w11 */           \
    STAGE_PJ(C_, 14); PAF(0, 0);                                               \
    WV(2); BAR(); GELU_HALF(1); ZERO_ACC1(); LGKM0(); BAR();/* w12 */          \
    PBX2(0, 0); MFMA16(0, acc2);                                               \
    STAGE_PJ(C_, 15); PAF(1, 1); PBX2(1, 1);                                   \
  } while (0)

  CHUNK_TAIL(0);
  WV(2); BAR(); MFMA16(1, acc2);            // w13
  STAGE_FC(1, 0); PAF(0, 2); PBX2(0, 2);
  WV(2); BAR(); MFMA16(0, acc2);            // w14
  STAGE_FC(1, 1); PAF(1, 3); PBX2(1, 3);
  WV(2); BAR(); MFMA16(1, acc2);            // w15
  STAGE_FC(1, 2); PAF(0, 0); PBX1(0, 0);

  // ================= chunks 1..2 =================
  for (int c = 1; c < 3; ++c) {
    WV(2); BAR(); MFMA16(0, acc1);          // w0
    STAGE_FC(c, 3); PAF(1, 1); PBX1(1, 1);
    WV(2); BAR(); MFMA16(1, acc1);          // w1
    STAGE_FC(c, 4); PAF(0, 2); PBX1(0, 2);
    WV(2); BAR(); MFMA16(0, acc1);          // w2
    STAGE_FC(c, 5); PAF(1, 3); PBX1(1, 3);
    WV(2); BAR(); MFMA16(1, acc1);          // w3
    STAGE_FC(c, 6); PAF(0, 0); PBX1(0, 4);
    WV(2); BAR(); MFMA16(0, acc1);          // w4
    STAGE_FC(c, 7); PAF(1, 1); PBX1(1, 5);
    WV(2); BAR(); MFMA16(1, acc1);          // w5
    STAGE_PJ(c, 8); PAF(0, 2); PBX1(0, 6);
    WV(2); BAR(); MFMA16(0, acc1);          // w6
    STAGE_PJ(c, 9); PAF(1, 3); PBX1(1, 7);
    WV(2); BAR(); MFMA16(1, acc1);          // w7
    STAGE_PJ(c, 10); PAF(0, 0); GELU_HALF(0);
    CHUNK_TAIL(c);
    WV(2); BAR(); MFMA16(1, acc2);          // w13
    STAGE_FC(c + 1, 0); PAF(0, 2); PBX2(0, 2);
    WV(2); BAR(); MFMA16(0, acc2);          // w14
    STAGE_FC(c + 1, 1); PAF(1, 3); PBX2(1, 3);
    WV(2); BAR(); MFMA16(1, acc2);          // w15
    STAGE_FC(c + 1, 2); PAF(0, 0); PBX1(0, 0);
  }

  // ================= chunk 3 (drain tail) =================
  {
    const int c = 3;
    WV(2); BAR(); MFMA16(0, acc1);
    STAGE_FC(c, 3); PAF(1, 1); PBX1(1, 1);
    WV(2); BAR(); MFMA16(1, acc1);
    STAGE_FC(c, 4); PAF(0, 2); PBX1(0, 2);
    WV(2); BAR(); MFMA16(0, acc1);
    STAGE_FC(c, 5); PAF(1, 3); PBX1(1, 3);
    WV(2); BAR(); MFMA16(1, acc1);
    STAGE_FC(c, 6); PAF(0, 0); PBX1(0, 4);
    WV(2); BAR(); MFMA16(0, acc1);
    STAGE_FC(c, 7); PAF(1, 1); PBX1(1, 5);
    WV(2); BAR(); MFMA16(1, acc1);
    STAGE_PJ(c, 8); PAF(0, 2); PBX1(0, 6);
    WV(2); BAR(); MFMA16(0, acc1);
    STAGE_PJ(c, 9); PAF(1, 3); PBX1(1, 7);
    WV(2); BAR(); MFMA16(1, acc1);
    STAGE_PJ(c, 10); PAF(0, 0); GELU_HALF(0);
    CHUNK_TAIL(c);
    WV(2); BAR(); MFMA16(1, acc2);          // w61: no stage
    PAF(0, 2); PBX2(0, 2);
    WV(0); BAR(); MFMA16(0, acc2);          // w62: drain S63 for pre-read
    PAF(1, 3); PBX2(1, 3);
    WV(0); BAR(); MFMA16(1, acc2);          // w63
  }

  // ---- epilogue: acc2[f][fm] -> out; d = q*32+(f&1)*16+(f>>1)*128+l4*4 ----
#pragma unroll
  for (int f = 0; f < 4; ++f) {
#pragma unroll
    for (int fm = 0; fm < 4; ++fm) {
      int m = m0 + mRow + fm * 16;
      int d = q * 32 + (f & 1) * 16 + (f >> 1) * 128 + l4 * 4;
      *(f32x4*)(out + ((size_t)(e * CAPN + m)) * DDIM + d) = acc2[f][fm];
    }
  }
}

extern "C" void kernel_launch(void* const* d_in, const int* in_sizes, int n_in,
                              void* d_out, int out_size, void* d_ws, size_t ws_size,
                              hipStream_t stream) {
  (void)in_sizes; (void)n_in; (void)out_size; (void)ws_size;
  const float* x     = (const float*)d_in[0];
  const float* wfc   = (const float*)d_in[1];   // [E][D][H]
  const float* wproj = (const float*)d_in[2];   // [E][H][D]
  float* out = (float*)d_out;

  __bf16* wfcT   = (__bf16*)d_ws;
  __bf16* wprojT = (__bf16*)((char*)d_ws + (size_t)NE * DDIM * HDIM * sizeof(__bf16));

  hipFuncSetAttribute((const void*)fused_mlp,
                      hipFuncAttributeMaxDynamicSharedMemorySize, LDS160);

  tcast_kernel<<<dim3(NE * 64), dim3(256), 0, stream>>>(wfc, wfcT, DDIM, HDIM);
  tcast_kernel<<<dim3(NE * 64), dim3(256), 0, stream>>>(wproj, wprojT, HDIM, DDIM);
  fused_mlp<<<dim3(NE * 32), dim3(512), LDS160, stream>>>(x, wfcT, wprojT, out);
}